// Round 1
// baseline (2135.885 us; speedup 1.0000x reference)
//
#include <hip/hip_runtime.h>
#include <hip/hip_bf16.h>
#include <float.h>

// Problem constants
#define E_  64
#define L_  256
#define D_  768
#define H_  12
#define DH_ 64
#define TD_ 2304     // 3*D
#define NEGV -10000.0f
#define EPS_ 1e-5f

__device__ __forceinline__ float wred_sum64(float v){
  #pragma unroll
  for (int o = 32; o > 0; o >>= 1) v += __shfl_xor(v, o, 64);
  return v;
}
__device__ __forceinline__ float wred_max64(float v){
  #pragma unroll
  for (int o = 32; o > 0; o >>= 1) v = fmaxf(v, __shfl_xor(v, o, 64));
  return v;
}

// msum[l] = -10000 * sum_s pm[s,l]
__global__ void masksum_kernel(const int* __restrict__ pm, float* __restrict__ msum){
  int l = threadIdx.x;
  int cnt = 0;
  #pragma unroll
  for (int s = 0; s < E_; ++s) cnt += (pm[s * L_ + l] != 0);
  msum[l] = NEGV * (float)cnt;
}

// C[M,N] = A[M,K] @ W[N,K]^T + bias[N]   (fp32, 64x64 tile, BK=16, 4x4 microtile)
__global__ __launch_bounds__(256) void gemm_nt_bias(
    const float* __restrict__ A, const float* __restrict__ W,
    const float* __restrict__ bias, float* __restrict__ C,
    int M, int N, int K){
  __shared__ float As[16][64];   // [k][m]
  __shared__ float Bs[16][64];   // [k][n]
  int tid = threadIdx.x;
  int tx = tid & 15, ty = tid >> 4;
  int n0 = blockIdx.x * 64, m0 = blockIdx.y * 64;
  int r = tid >> 2, c4 = (tid & 3) << 2;
  float acc[4][4] = {};
  for (int k0 = 0; k0 < K; k0 += 16){
    float4 a = *(const float4*)(A + (size_t)(m0 + r) * K + k0 + c4);
    float4 b = *(const float4*)(W + (size_t)(n0 + r) * K + k0 + c4);
    __syncthreads();           // previous tile fully consumed
    As[c4+0][r] = a.x; As[c4+1][r] = a.y; As[c4+2][r] = a.z; As[c4+3][r] = a.w;
    Bs[c4+0][r] = b.x; Bs[c4+1][r] = b.y; Bs[c4+2][r] = b.z; Bs[c4+3][r] = b.w;
    __syncthreads();
    #pragma unroll
    for (int kk = 0; kk < 16; ++kk){
      float4 av = *(const float4*)&As[kk][ty << 2];
      float4 bv = *(const float4*)&Bs[kk][tx << 2];
      float ar[4] = {av.x, av.y, av.z, av.w};
      float br[4] = {bv.x, bv.y, bv.z, bv.w};
      #pragma unroll
      for (int i2 = 0; i2 < 4; ++i2){
        #pragma unroll
        for (int j2 = 0; j2 < 4; ++j2)
          acc[i2][j2] = fmaf(ar[i2], br[j2], acc[i2][j2]);
      }
    }
  }
  float4 bb = *(const float4*)(bias + n0 + (tx << 2));
  #pragma unroll
  for (int i2 = 0; i2 < 4; ++i2){
    float4 o = {acc[i2][0] + bb.x, acc[i2][1] + bb.y, acc[i2][2] + bb.z, acc[i2][3] + bb.w};
    *(float4*)(C + (size_t)(m0 + (ty << 2) + i2) * N + n0 + (tx << 2)) = o;
  }
}

// rlog[h,i,j] = (1/64) * sum_{s,c} q[s,i,h,c]*k[s,j,h,c] + msum[j]
__global__ __launch_bounds__(256) void row_logits_kernel(
    const float* __restrict__ qkv, const float* __restrict__ msum,
    float* __restrict__ rlog){
  int h  = blockIdx.z;
  int j0 = blockIdx.x * 64, i0 = blockIdx.y * 64;
  __shared__ float Qs[64][80];   // [c][i] (padded rows: 80 floats, keeps 16B align)
  __shared__ float Ks[64][80];   // [c][j]
  int tid = threadIdx.x;
  int tx = tid & 15, ty = tid >> 4;
  int r = tid >> 2, cc = (tid & 3) << 4;
  const float* qb = qkv + h * DH_;
  const float* kb = qkv + D_ + h * DH_;
  float acc[4][4] = {};
  for (int s = 0; s < E_; ++s){
    size_t sb = (size_t)s * L_ * TD_;
    float4 qa[4], ka[4];
    #pragma unroll
    for (int u = 0; u < 4; ++u){
      qa[u] = *(const float4*)(qb + sb + (size_t)(i0 + r) * TD_ + cc + u * 4);
      ka[u] = *(const float4*)(kb + sb + (size_t)(j0 + r) * TD_ + cc + u * 4);
    }
    __syncthreads();
    #pragma unroll
    for (int u = 0; u < 4; ++u){
      int c = cc + u * 4;
      Qs[c+0][r] = qa[u].x; Qs[c+1][r] = qa[u].y; Qs[c+2][r] = qa[u].z; Qs[c+3][r] = qa[u].w;
      Ks[c+0][r] = ka[u].x; Ks[c+1][r] = ka[u].y; Ks[c+2][r] = ka[u].z; Ks[c+3][r] = ka[u].w;
    }
    __syncthreads();
    #pragma unroll 16
    for (int c = 0; c < 64; ++c){
      float4 av = *(const float4*)&Qs[c][ty << 2];
      float4 bv = *(const float4*)&Ks[c][tx << 2];
      float ar[4] = {av.x, av.y, av.z, av.w};
      float br[4] = {bv.x, bv.y, bv.z, bv.w};
      #pragma unroll
      for (int a2 = 0; a2 < 4; ++a2){
        #pragma unroll
        for (int b2 = 0; b2 < 4; ++b2)
          acc[a2][b2] = fmaf(ar[a2], br[b2], acc[a2][b2]);
      }
    }
  }
  const float sc = 1.0f / 64.0f;
  float4 ms = *(const float4*)(msum + j0 + (tx << 2));
  #pragma unroll
  for (int a2 = 0; a2 < 4; ++a2){
    int gi = i0 + (ty << 2) + a2;
    float4 o = {acc[a2][0]*sc + ms.x, acc[a2][1]*sc + ms.y,
                acc[a2][2]*sc + ms.z, acc[a2][3]*sc + ms.w};
    *(float4*)(rlog + ((size_t)h * L_ + gi) * L_ + j0 + (tx << 2)) = o;
  }
}

// softmax over j for each (h,i) row; writes row_maps (output 1)
__global__ __launch_bounds__(256) void row_softmax_kernel(
    const float* __restrict__ rlog, float* __restrict__ maps){
  int row = blockIdx.x;          // h*256 + i
  int t = threadIdx.x;
  float v = rlog[(size_t)row * L_ + t];
  __shared__ float red[8];
  float m = wred_max64(v);
  int wid = t >> 6;
  if ((t & 63) == 0) red[wid] = m;
  __syncthreads();
  float bm = fmaxf(fmaxf(red[0], red[1]), fmaxf(red[2], red[3]));
  float e = __expf(v - bm);
  float s = wred_sum64(e);
  if ((t & 63) == 0) red[4 + wid] = s;
  __syncthreads();
  float bs = (red[4] + red[5]) + (red[6] + red[7]);
  maps[(size_t)row * L_ + t] = e / bs;
}

// rowtmp[s,i,h,:] = x[s,i,h,:] + sum_j maps[h,i,j] * v[s,j,h,:]
__global__ __launch_bounds__(256) void row_pv_kernel(
    const float* __restrict__ qkv, const float* __restrict__ maps,
    const float* __restrict__ x, float* __restrict__ rowtmp){
  int s = blockIdx.x, h = blockIdx.y;
  int i = threadIdx.x;           // output row (location)
  __shared__ float Vs[64][64];   // [j][c]
  float acc[64] = {};
  const float* vb = qkv + 2 * D_ + h * DH_;
  const float* mrow = maps + ((size_t)h * L_ + i) * L_;
  for (int j0 = 0; j0 < L_; j0 += 64){
    __syncthreads();
    int r = i >> 2, cc = (i & 3) << 4;
    #pragma unroll
    for (int u = 0; u < 4; ++u)
      *(float4*)&Vs[r][cc + u*4] =
        *(const float4*)(vb + ((size_t)s * L_ + j0 + r) * TD_ + cc + u * 4);
    __syncthreads();
    for (int jc = 0; jc < 64; ++jc){
      float p = mrow[j0 + jc];
      #pragma unroll
      for (int u = 0; u < 16; ++u){
        float4 vv = *(const float4*)&Vs[jc][u * 4];
        acc[u*4+0] = fmaf(p, vv.x, acc[u*4+0]);
        acc[u*4+1] = fmaf(p, vv.y, acc[u*4+1]);
        acc[u*4+2] = fmaf(p, vv.z, acc[u*4+2]);
        acc[u*4+3] = fmaf(p, vv.w, acc[u*4+3]);
      }
    }
  }
  size_t base = ((size_t)s * L_ + i) * D_ + h * DH_;
  #pragma unroll
  for (int u = 0; u < 16; ++u){
    float4 xv = *(const float4*)(x + base + u * 4);
    float4 o = {xv.x + acc[u*4+0], xv.y + acc[u*4+1],
                xv.z + acc[u*4+2], xv.w + acc[u*4+3]};
    *(float4*)(rowtmp + base + u * 4) = o;
  }
}

// LayerNorm over last dim (768). If ADD, input is a+b.
template<bool ADD>
__global__ __launch_bounds__(256) void ln_kernel(
    const float* __restrict__ a, const float* __restrict__ b,
    const float* __restrict__ g, const float* __restrict__ be,
    float* __restrict__ out){
  int row = blockIdx.x;
  int t = threadIdx.x;
  const float* pa = a + (size_t)row * D_;
  const float* pb = ADD ? (b + (size_t)row * D_) : nullptr;
  float v[3];
  float s1 = 0.f, s2 = 0.f;
  #pragma unroll
  for (int u = 0; u < 3; ++u){
    int c = t + u * 256;
    float xv = pa[c];
    if (ADD) xv += pb[c];
    v[u] = xv; s1 += xv; s2 += xv * xv;
  }
  s1 = wred_sum64(s1); s2 = wred_sum64(s2);
  __shared__ float red[8];
  int wid = t >> 6;
  if ((t & 63) == 0){ red[wid] = s1; red[4 + wid] = s2; }
  __syncthreads();
  float ts1 = (red[0] + red[1]) + (red[2] + red[3]);
  float ts2 = (red[4] + red[5]) + (red[6] + red[7]);
  float mu = ts1 * (1.0f / D_);
  float var = ts2 * (1.0f / D_) - mu * mu;
  float rs = rsqrtf(var + EPS_);
  #pragma unroll
  for (int u = 0; u < 3; ++u){
    int c = t + u * 256;
    out[(size_t)row * D_ + c] = (v[u] - mu) * rs * g[c] + be[c];
  }
}

// Column attention, one block per (l, h): 64x64 scores over E, softmax over j.
__global__ __launch_bounds__(256) void col_attn_kernel(
    const float* __restrict__ qkv, const int* __restrict__ pm,
    float* __restrict__ colout){
  int l = blockIdx.x;
  int h = blockIdx.y;
  __shared__ float Qs[64][64];   // later reused for V
  __shared__ float Ks[64][64];
  __shared__ float Ps[64][65];
  int tid = threadIdx.x;
  int r = tid >> 2, cc = (tid & 3) << 4;
  const float* qb = qkv + h * DH_;
  const float* kb = qkv + D_ + h * DH_;
  const float* vb = qkv + 2 * D_ + h * DH_;
  size_t rowbase = ((size_t)r * L_ + l) * TD_;
  #pragma unroll
  for (int u = 0; u < 4; ++u){
    *(float4*)&Qs[r][cc + u*4] = *(const float4*)(qb + rowbase + cc + u * 4);
    *(float4*)&Ks[r][cc + u*4] = *(const float4*)(kb + rowbase + cc + u * 4);
  }
  __syncthreads();
  int i = tid >> 2, jq = tid & 3;
  float4 qreg[16];
  #pragma unroll
  for (int u = 0; u < 16; ++u) qreg[u] = *(const float4*)&Qs[i][u * 4];
  float vals[16];
  #pragma unroll
  for (int jj = 0; jj < 16; ++jj){
    int j = jq * 16 + jj;
    float dot = 0.f;
    #pragma unroll
    for (int u = 0; u < 16; ++u){
      float4 kv = *(const float4*)&Ks[j][u * 4];
      dot += qreg[u].x*kv.x + qreg[u].y*kv.y + qreg[u].z*kv.z + qreg[u].w*kv.w;
    }
    vals[jj] = dot * 0.125f + ((pm[j * L_ + l] != 0) ? NEGV : 0.f);
  }
  // softmax over j: each row i is held by 4 consecutive lanes (jq=0..3)
  float m = -FLT_MAX;
  #pragma unroll
  for (int jj = 0; jj < 16; ++jj) m = fmaxf(m, vals[jj]);
  m = fmaxf(m, __shfl_xor(m, 1, 64));
  m = fmaxf(m, __shfl_xor(m, 2, 64));
  float sum = 0.f;
  #pragma unroll
  for (int jj = 0; jj < 16; ++jj){ vals[jj] = __expf(vals[jj] - m); sum += vals[jj]; }
  sum += __shfl_xor(sum, 1, 64);
  sum += __shfl_xor(sum, 2, 64);
  float inv = 1.0f / sum;
  #pragma unroll
  for (int jj = 0; jj < 16; ++jj) Ps[i][jq * 16 + jj] = vals[jj] * inv;
  __syncthreads();
  // V into Qs (Q no longer needed)
  #pragma unroll
  for (int u = 0; u < 4; ++u)
    *(float4*)&Qs[r][cc + u*4] = *(const float4*)(vb + rowbase + cc + u * 4);
  __syncthreads();
  int cq = tid & 3;
  float acc[16] = {};
  for (int j = 0; j < 64; ++j){
    float p = Ps[i][j];
    #pragma unroll
    for (int u = 0; u < 4; ++u){
      float4 vv = *(const float4*)&Qs[j][cq * 16 + u * 4];
      acc[u*4+0] = fmaf(p, vv.x, acc[u*4+0]);
      acc[u*4+1] = fmaf(p, vv.y, acc[u*4+1]);
      acc[u*4+2] = fmaf(p, vv.z, acc[u*4+2]);
      acc[u*4+3] = fmaf(p, vv.w, acc[u*4+3]);
    }
  }
  size_t ob = ((size_t)i * L_ + l) * D_ + h * DH_ + cq * 16;
  #pragma unroll
  for (int u = 0; u < 4; ++u){
    float4 o = {acc[u*4+0], acc[u*4+1], acc[u*4+2], acc[u*4+3]};
    *(float4*)(colout + ob + u * 4) = o;
  }
}

extern "C" void kernel_launch(void* const* d_in, const int* in_sizes, int n_in,
                              void* d_out, int out_size, void* d_ws, size_t ws_size,
                              hipStream_t stream){
  (void)in_sizes; (void)n_in; (void)out_size; (void)ws_size;
  const float* x     = (const float*)d_in[0];
  const int*   pm    = (const int*)  d_in[1];
  const float* w_row = (const float*)d_in[2];
  const float* b_row = (const float*)d_in[3];
  const float* w_col = (const float*)d_in[4];
  const float* b_col = (const float*)d_in[5];
  const float* g1    = (const float*)d_in[6];
  const float* be1   = (const float*)d_in[7];
  const float* g2    = (const float*)d_in[8];
  const float* be2   = (const float*)d_in[9];

  float* out  = (float*)d_out;                       // [64,256,768]
  float* maps = out + (size_t)E_ * L_ * D_;          // [12,256,256]

  // ws layout (floats): qkv 37,748,736 | out1 12,582,912 | tmp 12,582,912
  //                     | msum 256 | rlog 786,432   => ~255 MB total
  float* F    = (float*)d_ws;
  float* qkv  = F;
  float* out1 = F + 37748736;
  float* tmpb = F + 50331648;   // rowtmp, later colout
  float* msum = F + 62914560;
  float* rlog = F + 62914816;

  const int M = E_ * L_;        // 16384

  masksum_kernel<<<1, 256, 0, stream>>>(pm, msum);
  gemm_nt_bias<<<dim3(TD_/64, M/64), 256, 0, stream>>>(x, w_row, b_row, qkv, M, TD_, D_);
  row_logits_kernel<<<dim3(4, 4, H_), 256, 0, stream>>>(qkv, msum, rlog);
  row_softmax_kernel<<<H_ * L_, 256, 0, stream>>>(rlog, maps);
  row_pv_kernel<<<dim3(E_, H_), 256, 0, stream>>>(qkv, maps, x, tmpb);
  ln_kernel<false><<<M, 256, 0, stream>>>(tmpb, nullptr, g1, be1, out1);
  gemm_nt_bias<<<dim3(TD_/64, M/64), 256, 0, stream>>>(out1, w_col, b_col, qkv, M, TD_, D_);
  col_attn_kernel<<<dim3(L_, H_), 256, 0, stream>>>(qkv, pm, tmpb);
  ln_kernel<true><<<M, 256, 0, stream>>>(out1, tmpb, g2, be2, out);
}

// Round 4
// 749.343 us; speedup vs baseline: 2.8503x; 2.8503x over previous
//
#include <hip/hip_runtime.h>
#include <hip/hip_bf16.h>
#include <float.h>

// Problem constants
#define E_  64
#define L_  256
#define D_  768
#define H_  12
#define DH_ 64
#define TD_ 2304     // 3*D
#define NEGV -10000.0f
#define EPS_ 1e-5f

#define GM 16384     // E_*L_
#define GN 2304      // TD_
#define GK 768       // D_

typedef __attribute__((ext_vector_type(8))) __bf16 bf16x8;
typedef __attribute__((ext_vector_type(4))) float f32x4;
typedef __attribute__((ext_vector_type(8))) unsigned short u16x8;

__device__ __forceinline__ float wred_sum64(float v){
  #pragma unroll
  for (int o = 32; o > 0; o >>= 1) v += __shfl_xor(v, o, 64);
  return v;
}
__device__ __forceinline__ float wred_max64(float v){
  #pragma unroll
  for (int o = 32; o > 0; o >>= 1) v = fmaxf(v, __shfl_xor(v, o, 64));
  return v;
}
__device__ __forceinline__ unsigned short f2bf(float f){
  unsigned int u = __float_as_uint(f);
  u += 0x7FFF + ((u >> 16) & 1);   // round-to-nearest-even
  return (unsigned short)(u >> 16);
}
__device__ __forceinline__ float bf2f(unsigned short s){
  return __uint_as_float(((unsigned int)s) << 16);
}

// fp32 -> bf16, 8 elems/thread, exact grid (n % 2048 == 0)
__global__ __launch_bounds__(256) void f2b_kernel(
    const float* __restrict__ in, unsigned short* __restrict__ out){
  size_t i = ((size_t)blockIdx.x * 256 + threadIdx.x) * 8;
  float4 a = *(const float4*)(in + i);
  float4 b = *(const float4*)(in + i + 4);
  u16x8 o;
  o[0]=f2bf(a.x); o[1]=f2bf(a.y); o[2]=f2bf(a.z); o[3]=f2bf(a.w);
  o[4]=f2bf(b.x); o[5]=f2bf(b.y); o[6]=f2bf(b.z); o[7]=f2bf(b.w);
  *(u16x8*)(out + i) = o;
}

// msum[l] = -10000 * sum_s pm[s,l]
__global__ void masksum_kernel(const int* __restrict__ pm, float* __restrict__ msum){
  int l = threadIdx.x;
  int cnt = 0;
  #pragma unroll
  for (int s = 0; s < E_; ++s) cnt += (pm[s * L_ + l] != 0);
  msum[l] = NEGV * (float)cnt;
}

// C[GM,GN] = A[GM,GK](bf16) @ W[GN,GK](bf16)^T + bias, fp32 out.
// m97 structure: 128x128 tile, BK=32, 4 waves 2x2, 16x16x32 bf16 MFMA,
// global_load_lds width-16 staging (linear LDS, wave-uniform dest base).
__global__ __launch_bounds__(256) void gemm_mfma_nt(
    const unsigned short* __restrict__ A,
    const unsigned short* __restrict__ W,
    const float* __restrict__ bias,
    float* __restrict__ C){
  __shared__ unsigned short As[128*32] __attribute__((aligned(16)));
  __shared__ unsigned short Bs[128*32] __attribute__((aligned(16)));
  int tid = threadIdx.x;
  int lane = tid & 63, wave = tid >> 6;
  int wr = wave >> 1, wc = wave & 1;
  int m0 = blockIdx.y * 128, n0 = blockIdx.x * 128;
  int col16 = lane & 15, kgrp = lane >> 4;

  f32x4 zero = {0.f, 0.f, 0.f, 0.f};
  f32x4 acc[4][4];
  #pragma unroll
  for (int mf = 0; mf < 4; ++mf)
    #pragma unroll
    for (int nf = 0; nf < 4; ++nf) acc[mf][nf] = zero;

  // staging: wave w covers tile rows [w*32, w*32+32); lane l -> row l>>2, kchunk (l&3)*8
  int srow = lane >> 2;
  int kchunk = (lane & 3) * 8;
  const unsigned short* Ag = A + (size_t)(m0 + wave * 32 + srow) * GK + kchunk;
  const unsigned short* Wg = W + (size_t)(n0 + wave * 32 + srow) * GK + kchunk;
  unsigned short* AsB = &As[(wave * 32) * 32];   // wave-uniform LDS base
  unsigned short* BsB = &Bs[(wave * 32) * 32];

  for (int k0 = 0; k0 < GK; k0 += 32) {
    __syncthreads();   // previous tile fully consumed
    __builtin_amdgcn_global_load_lds(
      (const __attribute__((address_space(1))) unsigned int*)(Ag + k0),
      (__attribute__((address_space(3))) unsigned int*)(AsB), 16, 0, 0);
    __builtin_amdgcn_global_load_lds(
      (const __attribute__((address_space(1))) unsigned int*)(Ag + 16 * GK + k0),
      (__attribute__((address_space(3))) unsigned int*)(AsB + 16 * 32), 16, 0, 0);
    __builtin_amdgcn_global_load_lds(
      (const __attribute__((address_space(1))) unsigned int*)(Wg + k0),
      (__attribute__((address_space(3))) unsigned int*)(BsB), 16, 0, 0);
    __builtin_amdgcn_global_load_lds(
      (const __attribute__((address_space(1))) unsigned int*)(Wg + 16 * GK + k0),
      (__attribute__((address_space(3))) unsigned int*)(BsB + 16 * 32), 16, 0, 0);
    __syncthreads();   // compiler drains vmcnt before barrier -> data visible
    bf16x8 af[4], bfr[4];
    #pragma unroll
    for (int mf = 0; mf < 4; ++mf)
      af[mf] = *(const bf16x8*)&As[(wr * 64 + mf * 16 + col16) * 32 + kgrp * 8];
    #pragma unroll
    for (int nf = 0; nf < 4; ++nf)
      bfr[nf] = *(const bf16x8*)&Bs[(wc * 64 + nf * 16 + col16) * 32 + kgrp * 8];
    #pragma unroll
    for (int mf = 0; mf < 4; ++mf)
      #pragma unroll
      for (int nf = 0; nf < 4; ++nf)
        acc[mf][nf] = __builtin_amdgcn_mfma_f32_16x16x32_bf16(af[mf], bfr[nf], acc[mf][nf], 0, 0, 0);
  }

  float bv[4];
  #pragma unroll
  for (int nf = 0; nf < 4; ++nf) bv[nf] = bias[n0 + wc * 64 + nf * 16 + col16];
  #pragma unroll
  for (int mf = 0; mf < 4; ++mf){
    int rbase = m0 + wr * 64 + mf * 16 + kgrp * 4;
    #pragma unroll
    for (int j = 0; j < 4; ++j){
      float* crow = C + (size_t)(rbase + j) * GN + n0 + wc * 64 + col16;
      #pragma unroll
      for (int nf = 0; nf < 4; ++nf)
        crow[nf * 16] = acc[mf][nf][j] + bv[nf];
    }
  }
}

// rlog[h,i,j] = (1/64) * sum_{s,c} q[s,i,h,c]*k[s,j,h,c] + msum[j]
__global__ __launch_bounds__(256) void row_logits_kernel(
    const float* __restrict__ qkv, const float* __restrict__ msum,
    float* __restrict__ rlog){
  int h  = blockIdx.z;
  int j0 = blockIdx.x * 64, i0 = blockIdx.y * 64;
  __shared__ float Qs[64][80];
  __shared__ float Ks[64][80];
  int tid = threadIdx.x;
  int tx = tid & 15, ty = tid >> 4;
  int r = tid >> 2, cc = (tid & 3) << 4;
  const float* qb = qkv + h * DH_;
  const float* kb = qkv + D_ + h * DH_;
  float acc[4][4] = {};
  for (int s = 0; s < E_; ++s){
    size_t sb = (size_t)s * L_ * TD_;
    float4 qa[4], ka[4];
    #pragma unroll
    for (int u = 0; u < 4; ++u){
      qa[u] = *(const float4*)(qb + sb + (size_t)(i0 + r) * TD_ + cc + u * 4);
      ka[u] = *(const float4*)(kb + sb + (size_t)(j0 + r) * TD_ + cc + u * 4);
    }
    __syncthreads();
    #pragma unroll
    for (int u = 0; u < 4; ++u){
      int c = cc + u * 4;
      Qs[c+0][r] = qa[u].x; Qs[c+1][r] = qa[u].y; Qs[c+2][r] = qa[u].z; Qs[c+3][r] = qa[u].w;
      Ks[c+0][r] = ka[u].x; Ks[c+1][r] = ka[u].y; Ks[c+2][r] = ka[u].z; Ks[c+3][r] = ka[u].w;
    }
    __syncthreads();
    #pragma unroll 16
    for (int c = 0; c < 64; ++c){
      float4 av = *(const float4*)&Qs[c][ty << 2];
      float4 bv = *(const float4*)&Ks[c][tx << 2];
      float ar[4] = {av.x, av.y, av.z, av.w};
      float br[4] = {bv.x, bv.y, bv.z, bv.w};
      #pragma unroll
      for (int a2 = 0; a2 < 4; ++a2){
        #pragma unroll
        for (int b2 = 0; b2 < 4; ++b2)
          acc[a2][b2] = fmaf(ar[a2], br[b2], acc[a2][b2]);
      }
    }
  }
  const float sc = 1.0f / 64.0f;
  float4 ms = *(const float4*)(msum + j0 + (tx << 2));
  #pragma unroll
  for (int a2 = 0; a2 < 4; ++a2){
    int gi = i0 + (ty << 2) + a2;
    float4 o = {acc[a2][0]*sc + ms.x, acc[a2][1]*sc + ms.y,
                acc[a2][2]*sc + ms.z, acc[a2][3]*sc + ms.w};
    *(float4*)(rlog + ((size_t)h * L_ + gi) * L_ + j0 + (tx << 2)) = o;
  }
}

// softmax over j for each (h,i) row; writes row_maps (output 1)
__global__ __launch_bounds__(256) void row_softmax_kernel(
    const float* __restrict__ rlog, float* __restrict__ maps){
  int row = blockIdx.x;
  int t = threadIdx.x;
  float v = rlog[(size_t)row * L_ + t];
  __shared__ float red[8];
  float m = wred_max64(v);
  int wid = t >> 6;
  if ((t & 63) == 0) red[wid] = m;
  __syncthreads();
  float bm = fmaxf(fmaxf(red[0], red[1]), fmaxf(red[2], red[3]));
  float e = __expf(v - bm);
  float s = wred_sum64(e);
  if ((t & 63) == 0) red[4 + wid] = s;
  __syncthreads();
  float bs = (red[4] + red[5]) + (red[6] + red[7]);
  maps[(size_t)row * L_ + t] = e / bs;
}

// rowtmp[s,i,h,:] = x[s,i,h,:] + sum_j maps[h,i,j] * v[s,j,h,:]
__global__ __launch_bounds__(256) void row_pv_kernel(
    const float* __restrict__ qkv, const float* __restrict__ maps,
    const float* __restrict__ x, float* __restrict__ rowtmp){
  int s = blockIdx.x, h = blockIdx.y;
  int i = threadIdx.x;
  __shared__ float Vs[64][64];
  float acc[64] = {};
  const float* vb = qkv + 2 * D_ + h * DH_;
  const float* mrow = maps + ((size_t)h * L_ + i) * L_;
  for (int j0 = 0; j0 < L_; j0 += 64){
    __syncthreads();
    int r = i >> 2, cc = (i & 3) << 4;
    #pragma unroll
    for (int u = 0; u < 4; ++u)
      *(float4*)&Vs[r][cc + u*4] =
        *(const float4*)(vb + ((size_t)s * L_ + j0 + r) * TD_ + cc + u * 4);
    __syncthreads();
    for (int jc = 0; jc < 64; ++jc){
      float p = mrow[j0 + jc];
      #pragma unroll
      for (int u = 0; u < 16; ++u){
        float4 vv = *(const float4*)&Vs[jc][u * 4];
        acc[u*4+0] = fmaf(p, vv.x, acc[u*4+0]);
        acc[u*4+1] = fmaf(p, vv.y, acc[u*4+1]);
        acc[u*4+2] = fmaf(p, vv.z, acc[u*4+2]);
        acc[u*4+3] = fmaf(p, vv.w, acc[u*4+3]);
      }
    }
  }
  size_t base = ((size_t)s * L_ + i) * D_ + h * DH_;
  #pragma unroll
  for (int u = 0; u < 16; ++u){
    float4 xv = *(const float4*)(x + base + u * 4);
    float4 o = {xv.x + acc[u*4+0], xv.y + acc[u*4+1],
                xv.z + acc[u*4+2], xv.w + acc[u*4+3]};
    *(float4*)(rowtmp + base + u * 4) = o;
  }
}

// LN1: reads fp32 rowtmp, writes bf16 only (feeds gemm2 and the ln2 residual)
__global__ __launch_bounds__(256) void ln1_kernel(
    const float* __restrict__ a,
    const float* __restrict__ g, const float* __restrict__ be,
    unsigned short* __restrict__ outb){
  int row = blockIdx.x;
  int t = threadIdx.x;
  const float* pa = a + (size_t)row * D_;
  float v[3];
  float s1 = 0.f, s2 = 0.f;
  #pragma unroll
  for (int u = 0; u < 3; ++u){
    int c = t + u * 256;
    float xv = pa[c];
    v[u] = xv; s1 += xv; s2 += xv * xv;
  }
  s1 = wred_sum64(s1); s2 = wred_sum64(s2);
  __shared__ float red[8];
  int wid = t >> 6;
  if ((t & 63) == 0){ red[wid] = s1; red[4 + wid] = s2; }
  __syncthreads();
  float ts1 = (red[0] + red[1]) + (red[2] + red[3]);
  float ts2 = (red[4] + red[5]) + (red[6] + red[7]);
  float mu = ts1 * (1.0f / D_);
  float var = ts2 * (1.0f / D_) - mu * mu;
  float rs = rsqrtf(var + EPS_);
  #pragma unroll
  for (int u = 0; u < 3; ++u){
    int c = t + u * 256;
    outb[(size_t)row * D_ + c] = f2bf((v[u] - mu) * rs * g[c] + be[c]);
  }
}

// LN2: reads bf16 out1 + fp32 colout, writes fp32 final output
__global__ __launch_bounds__(256) void ln2_kernel(
    const unsigned short* __restrict__ ab,
    const float* __restrict__ b,
    const float* __restrict__ g, const float* __restrict__ be,
    float* __restrict__ out){
  int row = blockIdx.x;
  int t = threadIdx.x;
  const unsigned short* pa = ab + (size_t)row * D_;
  const float* pb = b + (size_t)row * D_;
  float v[3];
  float s1 = 0.f, s2 = 0.f;
  #pragma unroll
  for (int u = 0; u < 3; ++u){
    int c = t + u * 256;
    float xv = bf2f(pa[c]) + pb[c];
    v[u] = xv; s1 += xv; s2 += xv * xv;
  }
  s1 = wred_sum64(s1); s2 = wred_sum64(s2);
  __shared__ float red[8];
  int wid = t >> 6;
  if ((t & 63) == 0){ red[wid] = s1; red[4 + wid] = s2; }
  __syncthreads();
  float ts1 = (red[0] + red[1]) + (red[2] + red[3]);
  float ts2 = (red[4] + red[5]) + (red[6] + red[7]);
  float mu = ts1 * (1.0f / D_);
  float var = ts2 * (1.0f / D_) - mu * mu;
  float rs = rsqrtf(var + EPS_);
  #pragma unroll
  for (int u = 0; u < 3; ++u){
    int c = t + u * 256;
    out[(size_t)row * D_ + c] = (v[u] - mu) * rs * g[c] + be[c];
  }
}

// Column attention, one block per (l, h): 64x64 scores over E, softmax over j.
__global__ __launch_bounds__(256) void col_attn_kernel(
    const float* __restrict__ qkv, const int* __restrict__ pm,
    float* __restrict__ colout){
  int l = blockIdx.x;
  int h = blockIdx.y;
  __shared__ float Qs[64][64];
  __shared__ float Ks[64][64];
  __shared__ float Ps[64][65];
  int tid = threadIdx.x;
  int r = tid >> 2, cc = (tid & 3) << 4;
  const float* qb = qkv + h * DH_;
  const float* kb = qkv + D_ + h * DH_;
  const float* vb = qkv + 2 * D_ + h * DH_;
  size_t rowbase = ((size_t)r * L_ + l) * TD_;
  #pragma unroll
  for (int u = 0; u < 4; ++u){
    *(float4*)&Qs[r][cc + u*4] = *(const float4*)(qb + rowbase + cc + u * 4);
    *(float4*)&Ks[r][cc + u*4] = *(const float4*)(kb + rowbase + cc + u * 4);
  }
  __syncthreads();
  int i = tid >> 2, jq = tid & 3;
  float4 qreg[16];
  #pragma unroll
  for (int u = 0; u < 16; ++u) qreg[u] = *(const float4*)&Qs[i][u * 4];
  float vals[16];
  #pragma unroll
  for (int jj = 0; jj < 16; ++jj){
    int j = jq * 16 + jj;
    float dot = 0.f;
    #pragma unroll
    for (int u = 0; u < 16; ++u){
      float4 kv = *(const float4*)&Ks[j][u * 4];
      dot += qreg[u].x*kv.x + qreg[u].y*kv.y + qreg[u].z*kv.z + qreg[u].w*kv.w;
    }
    vals[jj] = dot * 0.125f + ((pm[j * L_ + l] != 0) ? NEGV : 0.f);
  }
  float m = -FLT_MAX;
  #pragma unroll
  for (int jj = 0; jj < 16; ++jj) m = fmaxf(m, vals[jj]);
  m = fmaxf(m, __shfl_xor(m, 1, 64));
  m = fmaxf(m, __shfl_xor(m, 2, 64));
  float sum = 0.f;
  #pragma unroll
  for (int jj = 0; jj < 16; ++jj){ vals[jj] = __expf(vals[jj] - m); sum += vals[jj]; }
  sum += __shfl_xor(sum, 1, 64);
  sum += __shfl_xor(sum, 2, 64);
  float inv = 1.0f / sum;
  #pragma unroll
  for (int jj = 0; jj < 16; ++jj) Ps[i][jq * 16 + jj] = vals[jj] * inv;
  __syncthreads();
  #pragma unroll
  for (int u = 0; u < 4; ++u)
    *(float4*)&Qs[r][cc + u*4] = *(const float4*)(vb + rowbase + cc + u * 4);
  __syncthreads();
  int cq = tid & 3;
  float acc[16] = {};
  for (int j = 0; j < 64; ++j){
    float p = Ps[i][j];
    #pragma unroll
    for (int u = 0; u < 4; ++u){
      float4 vv = *(const float4*)&Qs[j][cq * 16 + u * 4];
      acc[u*4+0] = fmaf(p, vv.x, acc[u*4+0]);
      acc[u*4+1] = fmaf(p, vv.y, acc[u*4+1]);
      acc[u*4+2] = fmaf(p, vv.z, acc[u*4+2]);
      acc[u*4+3] = fmaf(p, vv.w, acc[u*4+3]);
    }
  }
  size_t ob = ((size_t)i * L_ + l) * D_ + h * DH_ + cq * 16;
  #pragma unroll
  for (int u = 0; u < 4; ++u){
    float4 o = {acc[u*4+0], acc[u*4+1], acc[u*4+2], acc[u*4+3]};
    *(float4*)(colout + ob + u * 4) = o;
  }
}

extern "C" void kernel_launch(void* const* d_in, const int* in_sizes, int n_in,
                              void* d_out, int out_size, void* d_ws, size_t ws_size,
                              hipStream_t stream){
  (void)in_sizes; (void)n_in; (void)out_size; (void)ws_size;
  const float* x     = (const float*)d_in[0];
  const int*   pm    = (const int*)  d_in[1];
  const float* w_row = (const float*)d_in[2];
  const float* b_row = (const float*)d_in[3];
  const float* w_col = (const float*)d_in[4];
  const float* b_col = (const float*)d_in[5];
  const float* g1    = (const float*)d_in[6];
  const float* be1   = (const float*)d_in[7];
  const float* g2    = (const float*)d_in[8];
  const float* be2   = (const float*)d_in[9];

  float* out  = (float*)d_out;                       // [64,256,768]
  float* maps = out + (size_t)E_ * L_ * D_;          // [12,256,256]

  // ws layout (float offsets) — total 59,179,264 f = 225.8 MiB
  // (round-0's 243 MiB footprint passed; round-1's 273.8 MiB core-dumped ->
  //  suspected ws overflow; keep well under)
  //   qkv   @ 0            (37,748,736 f)
  //   tmpb  @ 37,748,736   (12,582,912 f)  rowtmp, later colout; xb aliases 1st half
  //   out1b @ 50,331,648   (6,291,456 f = 12.58M bf16)
  //   msum  @ 56,623,104   (256 f)
  //   rlog  @ 56,623,360   (786,432 f)
  //   wrb   @ 57,409,792   (884,736 f = 1.77M bf16)
  //   wcb   @ 58,294,528   (884,736 f)
  float* F    = (float*)d_ws;
  float* qkv  = F;
  float* tmpb = F + 37748736;
  unsigned short* out1b = (unsigned short*)(F + 50331648);
  float* msum = F + 56623104;
  float* rlog = F + 56623360;
  unsigned short* wrb = (unsigned short*)(F + 57409792);
  unsigned short* wcb = (unsigned short*)(F + 58294528);
  unsigned short* xb  = (unsigned short*)tmpb;   // dead before rowtmp is written

  const int M = E_ * L_;        // 16384
  const int NX = M * D_;        // 12,582,912
  const int NW = TD_ * D_;      // 1,769,472

  masksum_kernel<<<1, 256, 0, stream>>>(pm, msum);
  f2b_kernel<<<NX / 2048, 256, 0, stream>>>(x, xb);
  f2b_kernel<<<NW / 2048, 256, 0, stream>>>(w_row, wrb);
  f2b_kernel<<<NW / 2048, 256, 0, stream>>>(w_col, wcb);

  gemm_mfma_nt<<<dim3(GN/128, GM/128), 256, 0, stream>>>(xb, wrb, b_row, qkv);
  row_logits_kernel<<<dim3(4, 4, H_), 256, 0, stream>>>(qkv, msum, rlog);
  row_softmax_kernel<<<H_ * L_, 256, 0, stream>>>(rlog, maps);
  row_pv_kernel<<<dim3(E_, H_), 256, 0, stream>>>(qkv, maps, x, tmpb);
  ln1_kernel<<<M, 256, 0, stream>>>(tmpb, g1, be1, out1b);
  gemm_mfma_nt<<<dim3(GN/128, GM/128), 256, 0, stream>>>(out1b, wcb, b_col, qkv);
  col_attn_kernel<<<dim3(L_, H_), 256, 0, stream>>>(qkv, pm, tmpb);
  ln2_kernel<<<M, 256, 0, stream>>>(out1b, tmpb, g2, be2, out);
}

// Round 5
// 530.213 us; speedup vs baseline: 4.0284x; 1.4133x over previous
//
#include <hip/hip_runtime.h>
#include <hip/hip_bf16.h>
#include <float.h>

// Problem constants
#define E_  64
#define L_  256
#define D_  768
#define H_  12
#define DH_ 64
#define TD_ 2304     // 3*D
#define NEGV -10000.0f
#define EPS_ 1e-5f

#define GM 16384     // E_*L_
#define GN 2304      // TD_
#define GK 768       // D_

#define RSPLIT 8     // split-K factor for row_logits (over s)

typedef __attribute__((ext_vector_type(8))) __bf16 bf16x8;
typedef __attribute__((ext_vector_type(4))) float f32x4;
typedef __attribute__((ext_vector_type(8))) unsigned short u16x8;

__device__ __forceinline__ float wred_sum64(float v){
  #pragma unroll
  for (int o = 32; o > 0; o >>= 1) v += __shfl_xor(v, o, 64);
  return v;
}
__device__ __forceinline__ float wred_max64(float v){
  #pragma unroll
  for (int o = 32; o > 0; o >>= 1) v = fmaxf(v, __shfl_xor(v, o, 64));
  return v;
}
__device__ __forceinline__ unsigned short f2bf(float f){
  unsigned int u = __float_as_uint(f);
  u += 0x7FFF + ((u >> 16) & 1);   // round-to-nearest-even
  return (unsigned short)(u >> 16);
}
__device__ __forceinline__ float bf2f(unsigned short s){
  return __uint_as_float(((unsigned int)s) << 16);
}

// fp32 -> bf16, 8 elems/thread, exact grid (n % 2048 == 0)
__global__ __launch_bounds__(256) void f2b_kernel(
    const float* __restrict__ in, unsigned short* __restrict__ out){
  size_t i = ((size_t)blockIdx.x * 256 + threadIdx.x) * 8;
  float4 a = *(const float4*)(in + i);
  float4 b = *(const float4*)(in + i + 4);
  u16x8 o;
  o[0]=f2bf(a.x); o[1]=f2bf(a.y); o[2]=f2bf(a.z); o[3]=f2bf(a.w);
  o[4]=f2bf(b.x); o[5]=f2bf(b.y); o[6]=f2bf(b.z); o[7]=f2bf(b.w);
  *(u16x8*)(out + i) = o;
}

// msum[l] = -10000 * sum_s pm[s,l]
__global__ void masksum_kernel(const int* __restrict__ pm, float* __restrict__ msum){
  int l = threadIdx.x;
  int cnt = 0;
  #pragma unroll
  for (int s = 0; s < E_; ++s) cnt += (pm[s * L_ + l] != 0);
  msum[l] = NEGV * (float)cnt;
}

// C[GM,GN](bf16) = A[GM,GK](bf16) @ W[GN,GK](bf16)^T + bias.
// m97 structure: 128x128 tile, BK=32, 4 waves 2x2, 16x16x32 bf16 MFMA.
__global__ __launch_bounds__(256) void gemm_mfma_nt(
    const unsigned short* __restrict__ A,
    const unsigned short* __restrict__ W,
    const float* __restrict__ bias,
    unsigned short* __restrict__ C){
  __shared__ unsigned short As[128*32] __attribute__((aligned(16)));
  __shared__ unsigned short Bs[128*32] __attribute__((aligned(16)));
  int tid = threadIdx.x;
  int lane = tid & 63, wave = tid >> 6;
  int wr = wave >> 1, wc = wave & 1;
  int m0 = blockIdx.y * 128, n0 = blockIdx.x * 128;
  int col16 = lane & 15, kgrp = lane >> 4;

  f32x4 zero = {0.f, 0.f, 0.f, 0.f};
  f32x4 acc[4][4];
  #pragma unroll
  for (int mf = 0; mf < 4; ++mf)
    #pragma unroll
    for (int nf = 0; nf < 4; ++nf) acc[mf][nf] = zero;

  int srow = lane >> 2;
  int kchunk = (lane & 3) * 8;
  const unsigned short* Ag = A + (size_t)(m0 + wave * 32 + srow) * GK + kchunk;
  const unsigned short* Wg = W + (size_t)(n0 + wave * 32 + srow) * GK + kchunk;
  unsigned short* AsB = &As[(wave * 32) * 32];   // wave-uniform LDS base
  unsigned short* BsB = &Bs[(wave * 32) * 32];

  for (int k0 = 0; k0 < GK; k0 += 32) {
    __syncthreads();
    __builtin_amdgcn_global_load_lds(
      (const __attribute__((address_space(1))) unsigned int*)(Ag + k0),
      (__attribute__((address_space(3))) unsigned int*)(AsB), 16, 0, 0);
    __builtin_amdgcn_global_load_lds(
      (const __attribute__((address_space(1))) unsigned int*)(Ag + 16 * GK + k0),
      (__attribute__((address_space(3))) unsigned int*)(AsB + 16 * 32), 16, 0, 0);
    __builtin_amdgcn_global_load_lds(
      (const __attribute__((address_space(1))) unsigned int*)(Wg + k0),
      (__attribute__((address_space(3))) unsigned int*)(BsB), 16, 0, 0);
    __builtin_amdgcn_global_load_lds(
      (const __attribute__((address_space(1))) unsigned int*)(Wg + 16 * GK + k0),
      (__attribute__((address_space(3))) unsigned int*)(BsB + 16 * 32), 16, 0, 0);
    __syncthreads();
    bf16x8 af[4], bfr[4];
    #pragma unroll
    for (int mf = 0; mf < 4; ++mf)
      af[mf] = *(const bf16x8*)&As[(wr * 64 + mf * 16 + col16) * 32 + kgrp * 8];
    #pragma unroll
    for (int nf = 0; nf < 4; ++nf)
      bfr[nf] = *(const bf16x8*)&Bs[(wc * 64 + nf * 16 + col16) * 32 + kgrp * 8];
    #pragma unroll
    for (int mf = 0; mf < 4; ++mf)
      #pragma unroll
      for (int nf = 0; nf < 4; ++nf)
        acc[mf][nf] = __builtin_amdgcn_mfma_f32_16x16x32_bf16(af[mf], bfr[nf], acc[mf][nf], 0, 0, 0);
  }

  float bv[4];
  #pragma unroll
  for (int nf = 0; nf < 4; ++nf) bv[nf] = bias[n0 + wc * 64 + nf * 16 + col16];
  #pragma unroll
  for (int mf = 0; mf < 4; ++mf){
    int rbase = m0 + wr * 64 + mf * 16 + kgrp * 4;
    #pragma unroll
    for (int j = 0; j < 4; ++j){
      unsigned short* crow = C + (size_t)(rbase + j) * GN + n0 + wc * 64 + col16;
      #pragma unroll
      for (int nf = 0; nf < 4; ++nf)
        crow[nf * 16] = f2bf(acc[mf][nf][j] + bv[nf]);
    }
  }
}

// rlogp[p,h,i,j] = sum_{s in split p, c} q[s,i,h,c]*k[s,j,h,c]   (bf16 MFMA)
// 128x128 tile per block (4 waves, 64x64 each), BK=64 (one s), split-K over s.
// LDS [128][64] bf16 with XOR swizzle (elem ^= (row&7)*8) on both stage-src and read.
__global__ __launch_bounds__(256) void row_logits_mfma(
    const unsigned short* __restrict__ qkvb, float* __restrict__ rlogp){
  __shared__ unsigned short As[128*64] __attribute__((aligned(16)));
  __shared__ unsigned short Bs[128*64] __attribute__((aligned(16)));
  int p = blockIdx.x;               // split index (s in [p*8, p*8+8))
  int tile = blockIdx.y;            // 2x2 tiles of 128
  int h = blockIdx.z;
  int i0 = (tile >> 1) * 128, j0 = (tile & 1) * 128;
  int tid = threadIdx.x;
  int lane = tid & 63, wave = tid >> 6;
  int wr = wave >> 1, wc = wave & 1;
  int lanelow = lane & 15, kgrp = lane >> 4;

  f32x4 zero = {0.f, 0.f, 0.f, 0.f};
  f32x4 acc[4][4];
  #pragma unroll
  for (int mf = 0; mf < 4; ++mf)
    #pragma unroll
    for (int nf = 0; nf < 4; ++nf) acc[mf][nf] = zero;

  // staging indices: call q covers chunks q*256 + tid; chunk -> row=chunk>>3, cb8=chunk&7
  int cb8 = tid & 7;
  const unsigned short* qb = qkvb + h * DH_;         // Q part
  const unsigned short* kb = qkvb + D_ + h * DH_;    // K part

  for (int ss = 0; ss < E_ / RSPLIT; ++ss){
    int s = p * (E_ / RSPLIT) + ss;
    size_t sb = (size_t)s * L_ * TD_;
    __syncthreads();
    #pragma unroll
    for (int q = 0; q < 4; ++q){
      int row = q * 32 + (tid >> 3);
      int srcoff = (cb8 * 8) ^ ((row & 7) * 8);      // pre-swizzled source
      unsigned short* ldsA = &As[(q * 256 + wave * 64) * 8];  // wave-uniform base
      unsigned short* ldsB = &Bs[(q * 256 + wave * 64) * 8];
      __builtin_amdgcn_global_load_lds(
        (const __attribute__((address_space(1))) unsigned int*)(qb + sb + (size_t)(i0 + row) * TD_ + srcoff),
        (__attribute__((address_space(3))) unsigned int*)ldsA, 16, 0, 0);
      __builtin_amdgcn_global_load_lds(
        (const __attribute__((address_space(1))) unsigned int*)(kb + sb + (size_t)(j0 + row) * TD_ + srcoff),
        (__attribute__((address_space(3))) unsigned int*)ldsB, 16, 0, 0);
    }
    __syncthreads();
    #pragma unroll
    for (int c0 = 0; c0 < 64; c0 += 32){
      bf16x8 af[4], bfr[4];
      #pragma unroll
      for (int mf = 0; mf < 4; ++mf){
        int row = wr * 64 + mf * 16 + lanelow;
        af[mf] = *(const bf16x8*)&As[row * 64 + ((c0 + kgrp * 8) ^ ((row & 7) * 8))];
      }
      #pragma unroll
      for (int nf = 0; nf < 4; ++nf){
        int row = wc * 64 + nf * 16 + lanelow;
        bfr[nf] = *(const bf16x8*)&Bs[row * 64 + ((c0 + kgrp * 8) ^ ((row & 7) * 8))];
      }
      #pragma unroll
      for (int mf = 0; mf < 4; ++mf)
        #pragma unroll
        for (int nf = 0; nf < 4; ++nf)
          acc[mf][nf] = __builtin_amdgcn_mfma_f32_16x16x32_bf16(af[mf], bfr[nf], acc[mf][nf], 0, 0, 0);
    }
  }

  float* outp = rlogp + ((size_t)p * H_ + h) * (L_ * L_);
  #pragma unroll
  for (int mf = 0; mf < 4; ++mf){
    int ibase = i0 + wr * 64 + mf * 16 + kgrp * 4;
    #pragma unroll
    for (int j2 = 0; j2 < 4; ++j2){
      float* orow = outp + (size_t)(ibase + j2) * L_ + j0 + wc * 64 + lanelow;
      #pragma unroll
      for (int nf = 0; nf < 4; ++nf)
        orow[nf * 16] = acc[mf][nf][j2];
    }
  }
}

// softmax over j: sums RSPLIT partials, scales by 1/64, adds msum[j]
__global__ __launch_bounds__(256) void row_softmax_kernel(
    const float* __restrict__ rlogp, const float* __restrict__ msum,
    float* __restrict__ maps){
  int row = blockIdx.x;          // h*256 + i
  int t = threadIdx.x;
  float v = 0.f;
  #pragma unroll
  for (int pp = 0; pp < RSPLIT; ++pp)
    v += rlogp[(size_t)pp * (H_ * L_ * L_) + (size_t)row * L_ + t];
  v = v * (1.0f / 64.0f) + msum[t];
  __shared__ float red[8];
  float m = wred_max64(v);
  int wid = t >> 6;
  if ((t & 63) == 0) red[wid] = m;
  __syncthreads();
  float bm = fmaxf(fmaxf(red[0], red[1]), fmaxf(red[2], red[3]));
  float e = __expf(v - bm);
  float s = wred_sum64(e);
  if ((t & 63) == 0) red[4 + wid] = s;
  __syncthreads();
  float bs = (red[4] + red[5]) + (red[6] + red[7]);
  maps[(size_t)row * L_ + t] = e / bs;
}

// rowtmp[s,i,h,:] = x[s,i,h,:] + sum_j maps[h,i,j] * v[s,j,h,:]   (V in bf16)
__global__ __launch_bounds__(256) void row_pv_kernel(
    const unsigned short* __restrict__ qkvb, const float* __restrict__ maps,
    const float* __restrict__ x, float* __restrict__ rowtmp){
  int s = blockIdx.x, h = blockIdx.y;
  int i = threadIdx.x;
  __shared__ float Vs[64][64];
  float acc[64] = {};
  const unsigned short* vb = qkvb + 2 * D_ + h * DH_;
  const float* mrow = maps + ((size_t)h * L_ + i) * L_;
  for (int j0 = 0; j0 < L_; j0 += 64){
    __syncthreads();
    int r = i >> 2, cc = (i & 3) << 4;
    #pragma unroll
    for (int u = 0; u < 2; ++u){
      u16x8 raw = *(const u16x8*)(vb + ((size_t)s * L_ + j0 + r) * TD_ + cc + u * 8);
      #pragma unroll
      for (int e = 0; e < 8; ++e) Vs[r][cc + u * 8 + e] = bf2f(raw[e]);
    }
    __syncthreads();
    for (int jc = 0; jc < 64; ++jc){
      float p = mrow[j0 + jc];
      #pragma unroll
      for (int u = 0; u < 16; ++u){
        float4 vv = *(const float4*)&Vs[jc][u * 4];
        acc[u*4+0] = fmaf(p, vv.x, acc[u*4+0]);
        acc[u*4+1] = fmaf(p, vv.y, acc[u*4+1]);
        acc[u*4+2] = fmaf(p, vv.z, acc[u*4+2]);
        acc[u*4+3] = fmaf(p, vv.w, acc[u*4+3]);
      }
    }
  }
  size_t base = ((size_t)s * L_ + i) * D_ + h * DH_;
  #pragma unroll
  for (int u = 0; u < 16; ++u){
    float4 xv = *(const float4*)(x + base + u * 4);
    float4 o = {xv.x + acc[u*4+0], xv.y + acc[u*4+1],
                xv.z + acc[u*4+2], xv.w + acc[u*4+3]};
    *(float4*)(rowtmp + base + u * 4) = o;
  }
}

// LN1: reads fp32 rowtmp, writes bf16 only (feeds gemm2 and the ln2 residual)
__global__ __launch_bounds__(256) void ln1_kernel(
    const float* __restrict__ a,
    const float* __restrict__ g, const float* __restrict__ be,
    unsigned short* __restrict__ outb){
  int row = blockIdx.x;
  int t = threadIdx.x;
  const float* pa = a + (size_t)row * D_;
  float v[3];
  float s1 = 0.f, s2 = 0.f;
  #pragma unroll
  for (int u = 0; u < 3; ++u){
    int c = t + u * 256;
    float xv = pa[c];
    v[u] = xv; s1 += xv; s2 += xv * xv;
  }
  s1 = wred_sum64(s1); s2 = wred_sum64(s2);
  __shared__ float red[8];
  int wid = t >> 6;
  if ((t & 63) == 0){ red[wid] = s1; red[4 + wid] = s2; }
  __syncthreads();
  float ts1 = (red[0] + red[1]) + (red[2] + red[3]);
  float ts2 = (red[4] + red[5]) + (red[6] + red[7]);
  float mu = ts1 * (1.0f / D_);
  float var = ts2 * (1.0f / D_) - mu * mu;
  float rs = rsqrtf(var + EPS_);
  #pragma unroll
  for (int u = 0; u < 3; ++u){
    int c = t + u * 256;
    outb[(size_t)row * D_ + c] = f2bf((v[u] - mu) * rs * g[c] + be[c]);
  }
}

// LN2: reads bf16 out1 + fp32 colout, writes fp32 final output
__global__ __launch_bounds__(256) void ln2_kernel(
    const unsigned short* __restrict__ ab,
    const float* __restrict__ b,
    const float* __restrict__ g, const float* __restrict__ be,
    float* __restrict__ out){
  int row = blockIdx.x;
  int t = threadIdx.x;
  const unsigned short* pa = ab + (size_t)row * D_;
  const float* pb = b + (size_t)row * D_;
  float v[3];
  float s1 = 0.f, s2 = 0.f;
  #pragma unroll
  for (int u = 0; u < 3; ++u){
    int c = t + u * 256;
    float xv = bf2f(pa[c]) + pb[c];
    v[u] = xv; s1 += xv; s2 += xv * xv;
  }
  s1 = wred_sum64(s1); s2 = wred_sum64(s2);
  __shared__ float red[8];
  int wid = t >> 6;
  if ((t & 63) == 0){ red[wid] = s1; red[4 + wid] = s2; }
  __syncthreads();
  float ts1 = (red[0] + red[1]) + (red[2] + red[3]);
  float ts2 = (red[4] + red[5]) + (red[6] + red[7]);
  float mu = ts1 * (1.0f / D_);
  float var = ts2 * (1.0f / D_) - mu * mu;
  float rs = rsqrtf(var + EPS_);
  #pragma unroll
  for (int u = 0; u < 3; ++u){
    int c = t + u * 256;
    out[(size_t)row * D_ + c] = (v[u] - mu) * rs * g[c] + be[c];
  }
}

// Column attention, one block per (l, h): 64x64 scores over E, softmax over j. (qkv in bf16)
__global__ __launch_bounds__(256) void col_attn_kernel(
    const unsigned short* __restrict__ qkvb, const int* __restrict__ pm,
    float* __restrict__ colout){
  int l = blockIdx.x;
  int h = blockIdx.y;
  __shared__ float Qs[64][64];
  __shared__ float Ks[64][64];
  __shared__ float Ps[64][65];
  int tid = threadIdx.x;
  int r = tid >> 2, cc = (tid & 3) << 4;
  const unsigned short* qb = qkvb + h * DH_;
  const unsigned short* kb = qkvb + D_ + h * DH_;
  const unsigned short* vb = qkvb + 2 * D_ + h * DH_;
  size_t rowbase = ((size_t)r * L_ + l) * TD_;
  #pragma unroll
  for (int u = 0; u < 2; ++u){
    u16x8 rq = *(const u16x8*)(qb + rowbase + cc + u * 8);
    u16x8 rk = *(const u16x8*)(kb + rowbase + cc + u * 8);
    #pragma unroll
    for (int e = 0; e < 8; ++e){
      Qs[r][cc + u * 8 + e] = bf2f(rq[e]);
      Ks[r][cc + u * 8 + e] = bf2f(rk[e]);
    }
  }
  __syncthreads();
  int i = tid >> 2, jq = tid & 3;
  float4 qreg[16];
  #pragma unroll
  for (int u = 0; u < 16; ++u) qreg[u] = *(const float4*)&Qs[i][u * 4];
  float vals[16];
  #pragma unroll
  for (int jj = 0; jj < 16; ++jj){
    int j = jq * 16 + jj;
    float dot = 0.f;
    #pragma unroll
    for (int u = 0; u < 16; ++u){
      float4 kv = *(const float4*)&Ks[j][u * 4];
      dot += qreg[u].x*kv.x + qreg[u].y*kv.y + qreg[u].z*kv.z + qreg[u].w*kv.w;
    }
    vals[jj] = dot * 0.125f + ((pm[j * L_ + l] != 0) ? NEGV : 0.f);
  }
  float m = -FLT_MAX;
  #pragma unroll
  for (int jj = 0; jj < 16; ++jj) m = fmaxf(m, vals[jj]);
  m = fmaxf(m, __shfl_xor(m, 1, 64));
  m = fmaxf(m, __shfl_xor(m, 2, 64));
  float sum = 0.f;
  #pragma unroll
  for (int jj = 0; jj < 16; ++jj){ vals[jj] = __expf(vals[jj] - m); sum += vals[jj]; }
  sum += __shfl_xor(sum, 1, 64);
  sum += __shfl_xor(sum, 2, 64);
  float inv = 1.0f / sum;
  #pragma unroll
  for (int jj = 0; jj < 16; ++jj) Ps[i][jq * 16 + jj] = vals[jj] * inv;
  __syncthreads();
  #pragma unroll
  for (int u = 0; u < 2; ++u){
    u16x8 rv = *(const u16x8*)(vb + rowbase + cc + u * 8);
    #pragma unroll
    for (int e = 0; e < 8; ++e) Qs[r][cc + u * 8 + e] = bf2f(rv[e]);
  }
  __syncthreads();
  int cq = tid & 3;
  float acc[16] = {};
  for (int j = 0; j < 64; ++j){
    float p = Ps[i][j];
    #pragma unroll
    for (int u = 0; u < 4; ++u){
      float4 vv = *(const float4*)&Qs[j][cq * 16 + u * 4];
      acc[u*4+0] = fmaf(p, vv.x, acc[u*4+0]);
      acc[u*4+1] = fmaf(p, vv.y, acc[u*4+1]);
      acc[u*4+2] = fmaf(p, vv.z, acc[u*4+2]);
      acc[u*4+3] = fmaf(p, vv.w, acc[u*4+3]);
    }
  }
  size_t ob = ((size_t)i * L_ + l) * D_ + h * DH_ + cq * 16;
  #pragma unroll
  for (int u = 0; u < 4; ++u){
    float4 o = {acc[u*4+0], acc[u*4+1], acc[u*4+2], acc[u*4+3]};
    *(float4*)(colout + ob + u * 4) = o;
  }
}

extern "C" void kernel_launch(void* const* d_in, const int* in_sizes, int n_in,
                              void* d_out, int out_size, void* d_ws, size_t ws_size,
                              hipStream_t stream){
  (void)in_sizes; (void)n_in; (void)out_size; (void)ws_size;
  const float* x     = (const float*)d_in[0];
  const int*   pm    = (const int*)  d_in[1];
  const float* w_row = (const float*)d_in[2];
  const float* b_row = (const float*)d_in[3];
  const float* w_col = (const float*)d_in[4];
  const float* b_col = (const float*)d_in[5];
  const float* g1    = (const float*)d_in[6];
  const float* be1   = (const float*)d_in[7];
  const float* g2    = (const float*)d_in[8];
  const float* be2   = (const float*)d_in[9];

  float* out  = (float*)d_out;                       // [64,256,768]
  float* maps = out + (size_t)E_ * L_ * D_;          // [12,256,256]

  // ws layout (float offsets) — total 45,809,920 f = 174.8 MiB (< proven 243 MiB)
  //   qkvb  @ 0            (37.75M bf16 = 18,874,368 f)
  //   tmpb  @ 18,874,368   (12,582,912 f)  rowtmp, later colout; xb aliases 1st half
  //   out1b @ 31,457,280   (12.58M bf16 = 6,291,456 f)
  //   msum  @ 37,748,736   (256 f)
  //   rlogp @ 37,748,992   (8*786,432 = 6,291,456 f)
  //   wrb   @ 44,040,448   (884,736 f)
  //   wcb   @ 44,925,184   (884,736 f)
  float* F    = (float*)d_ws;
  unsigned short* qkvb = (unsigned short*)F;
  float* tmpb = F + 18874368;
  unsigned short* out1b = (unsigned short*)(F + 31457280);
  float* msum = F + 37748736;
  float* rlogp = F + 37748992;
  unsigned short* wrb = (unsigned short*)(F + 44040448);
  unsigned short* wcb = (unsigned short*)(F + 44925184);
  unsigned short* xb  = (unsigned short*)tmpb;   // dead before rowtmp is written

  const int M = E_ * L_;        // 16384
  const int NX = M * D_;        // 12,582,912
  const int NW = TD_ * D_;      // 1,769,472

  masksum_kernel<<<1, 256, 0, stream>>>(pm, msum);
  f2b_kernel<<<NX / 2048, 256, 0, stream>>>(x, xb);
  f2b_kernel<<<NW / 2048, 256, 0, stream>>>(w_row, wrb);
  f2b_kernel<<<NW / 2048, 256, 0, stream>>>(w_col, wcb);

  gemm_mfma_nt<<<dim3(GN/128, GM/128), 256, 0, stream>>>(xb, wrb, b_row, qkvb);
  row_logits_mfma<<<dim3(RSPLIT, 4, H_), 256, 0, stream>>>(qkvb, rlogp);
  row_softmax_kernel<<<H_ * L_, 256, 0, stream>>>(rlogp, msum, maps);
  row_pv_kernel<<<dim3(E_, H_), 256, 0, stream>>>(qkvb, maps, x, tmpb);
  ln1_kernel<<<M, 256, 0, stream>>>(tmpb, g1, be1, out1b);
  gemm_mfma_nt<<<dim3(GN/128, GM/128), 256, 0, stream>>>(out1b, wcb, b_col, qkvb);
  col_attn_kernel<<<dim3(L_, H_), 256, 0, stream>>>(qkvb, pm, tmpb);
  ln2_kernel<<<M, 256, 0, stream>>>(out1b, tmpb, g2, be2, out);
}

// Round 6
// 408.450 us; speedup vs baseline: 5.2292x; 1.2981x over previous
//
#include <hip/hip_runtime.h>
#include <hip/hip_bf16.h>
#include <float.h>

// Problem constants
#define E_  64
#define L_  256
#define D_  768
#define H_  12
#define DH_ 64
#define TD_ 2304     // 3*D
#define NEGV -10000.0f
#define EPS_ 1e-5f

#define GM 16384     // E_*L_
#define GN 2304      // TD_
#define GK 768       // D_

#define RSPLIT 8     // split-K factor for row_logits (over s)

typedef __attribute__((ext_vector_type(8))) __bf16 bf16x8;
typedef __attribute__((ext_vector_type(4))) float f32x4;
typedef __attribute__((ext_vector_type(8))) unsigned short u16x8;

__device__ __forceinline__ float wred_sum64(float v){
  #pragma unroll
  for (int o = 32; o > 0; o >>= 1) v += __shfl_xor(v, o, 64);
  return v;
}
__device__ __forceinline__ float wred_max64(float v){
  #pragma unroll
  for (int o = 32; o > 0; o >>= 1) v = fmaxf(v, __shfl_xor(v, o, 64));
  return v;
}
__device__ __forceinline__ unsigned short f2bf(float f){
  unsigned int u = __float_as_uint(f);
  u += 0x7FFF + ((u >> 16) & 1);   // round-to-nearest-even
  return (unsigned short)(u >> 16);
}
__device__ __forceinline__ float bf2f(unsigned short s){
  return __uint_as_float(((unsigned int)s) << 16);
}

// fp32 -> bf16, 8 elems/thread, exact grid (n % 2048 == 0)
__global__ __launch_bounds__(256) void f2b_kernel(
    const float* __restrict__ in, unsigned short* __restrict__ out){
  size_t i = ((size_t)blockIdx.x * 256 + threadIdx.x) * 8;
  float4 a = *(const float4*)(in + i);
  float4 b = *(const float4*)(in + i + 4);
  u16x8 o;
  o[0]=f2bf(a.x); o[1]=f2bf(a.y); o[2]=f2bf(a.z); o[3]=f2bf(a.w);
  o[4]=f2bf(b.x); o[5]=f2bf(b.y); o[6]=f2bf(b.z); o[7]=f2bf(b.w);
  *(u16x8*)(out + i) = o;
}

// msum[l] = -10000 * sum_s pm[s,l]
__global__ void masksum_kernel(const int* __restrict__ pm, float* __restrict__ msum){
  int l = threadIdx.x;
  int cnt = 0;
  #pragma unroll
  for (int s = 0; s < E_; ++s) cnt += (pm[s * L_ + l] != 0);
  msum[l] = NEGV * (float)cnt;
}

// C[GM,GN](bf16) = A[GM,GK](bf16) @ W[GN,GK](bf16)^T + bias.
__global__ __launch_bounds__(256) void gemm_mfma_nt(
    const unsigned short* __restrict__ A,
    const unsigned short* __restrict__ W,
    const float* __restrict__ bias,
    unsigned short* __restrict__ C){
  __shared__ unsigned short As[128*32] __attribute__((aligned(16)));
  __shared__ unsigned short Bs[128*32] __attribute__((aligned(16)));
  int tid = threadIdx.x;
  int lane = tid & 63, wave = tid >> 6;
  int wr = wave >> 1, wc = wave & 1;
  int m0 = blockIdx.y * 128, n0 = blockIdx.x * 128;
  int col16 = lane & 15, kgrp = lane >> 4;

  f32x4 zero = {0.f, 0.f, 0.f, 0.f};
  f32x4 acc[4][4];
  #pragma unroll
  for (int mf = 0; mf < 4; ++mf)
    #pragma unroll
    for (int nf = 0; nf < 4; ++nf) acc[mf][nf] = zero;

  int srow = lane >> 2;
  int kchunk = (lane & 3) * 8;
  const unsigned short* Ag = A + (size_t)(m0 + wave * 32 + srow) * GK + kchunk;
  const unsigned short* Wg = W + (size_t)(n0 + wave * 32 + srow) * GK + kchunk;
  unsigned short* AsB = &As[(wave * 32) * 32];   // wave-uniform LDS base
  unsigned short* BsB = &Bs[(wave * 32) * 32];

  for (int k0 = 0; k0 < GK; k0 += 32) {
    __syncthreads();
    __builtin_amdgcn_global_load_lds(
      (const __attribute__((address_space(1))) unsigned int*)(Ag + k0),
      (__attribute__((address_space(3))) unsigned int*)(AsB), 16, 0, 0);
    __builtin_amdgcn_global_load_lds(
      (const __attribute__((address_space(1))) unsigned int*)(Ag + 16 * GK + k0),
      (__attribute__((address_space(3))) unsigned int*)(AsB + 16 * 32), 16, 0, 0);
    __builtin_amdgcn_global_load_lds(
      (const __attribute__((address_space(1))) unsigned int*)(Wg + k0),
      (__attribute__((address_space(3))) unsigned int*)(BsB), 16, 0, 0);
    __builtin_amdgcn_global_load_lds(
      (const __attribute__((address_space(1))) unsigned int*)(Wg + 16 * GK + k0),
      (__attribute__((address_space(3))) unsigned int*)(BsB + 16 * 32), 16, 0, 0);
    __syncthreads();
    bf16x8 af[4], bfr[4];
    #pragma unroll
    for (int mf = 0; mf < 4; ++mf)
      af[mf] = *(const bf16x8*)&As[(wr * 64 + mf * 16 + col16) * 32 + kgrp * 8];
    #pragma unroll
    for (int nf = 0; nf < 4; ++nf)
      bfr[nf] = *(const bf16x8*)&Bs[(wc * 64 + nf * 16 + col16) * 32 + kgrp * 8];
    #pragma unroll
    for (int mf = 0; mf < 4; ++mf)
      #pragma unroll
      for (int nf = 0; nf < 4; ++nf)
        acc[mf][nf] = __builtin_amdgcn_mfma_f32_16x16x32_bf16(af[mf], bfr[nf], acc[mf][nf], 0, 0, 0);
  }

  float bv[4];
  #pragma unroll
  for (int nf = 0; nf < 4; ++nf) bv[nf] = bias[n0 + wc * 64 + nf * 16 + col16];
  #pragma unroll
  for (int mf = 0; mf < 4; ++mf){
    int rbase = m0 + wr * 64 + mf * 16 + kgrp * 4;
    #pragma unroll
    for (int j = 0; j < 4; ++j){
      unsigned short* crow = C + (size_t)(rbase + j) * GN + n0 + wc * 64 + col16;
      #pragma unroll
      for (int nf = 0; nf < 4; ++nf)
        crow[nf * 16] = f2bf(acc[mf][nf][j] + bv[nf]);
    }
  }
}

// rlogp[p,h,i,j] = sum_{s in split p, c} q[s,i,h,c]*k[s,j,h,c]   (bf16 MFMA)
__global__ __launch_bounds__(256) void row_logits_mfma(
    const unsigned short* __restrict__ qkvb, float* __restrict__ rlogp){
  __shared__ unsigned short As[128*64] __attribute__((aligned(16)));
  __shared__ unsigned short Bs[128*64] __attribute__((aligned(16)));
  int p = blockIdx.x;
  int tile = blockIdx.y;
  int h = blockIdx.z;
  int i0 = (tile >> 1) * 128, j0 = (tile & 1) * 128;
  int tid = threadIdx.x;
  int lane = tid & 63, wave = tid >> 6;
  int wr = wave >> 1, wc = wave & 1;
  int lanelow = lane & 15, kgrp = lane >> 4;

  f32x4 zero = {0.f, 0.f, 0.f, 0.f};
  f32x4 acc[4][4];
  #pragma unroll
  for (int mf = 0; mf < 4; ++mf)
    #pragma unroll
    for (int nf = 0; nf < 4; ++nf) acc[mf][nf] = zero;

  int cb8 = tid & 7;
  const unsigned short* qb = qkvb + h * DH_;
  const unsigned short* kb = qkvb + D_ + h * DH_;

  for (int ss = 0; ss < E_ / RSPLIT; ++ss){
    int s = p * (E_ / RSPLIT) + ss;
    size_t sb = (size_t)s * L_ * TD_;
    __syncthreads();
    #pragma unroll
    for (int q = 0; q < 4; ++q){
      int row = q * 32 + (tid >> 3);
      int srcoff = (cb8 * 8) ^ ((row & 7) * 8);
      unsigned short* ldsA = &As[(q * 256 + wave * 64) * 8];
      unsigned short* ldsB = &Bs[(q * 256 + wave * 64) * 8];
      __builtin_amdgcn_global_load_lds(
        (const __attribute__((address_space(1))) unsigned int*)(qb + sb + (size_t)(i0 + row) * TD_ + srcoff),
        (__attribute__((address_space(3))) unsigned int*)ldsA, 16, 0, 0);
      __builtin_amdgcn_global_load_lds(
        (const __attribute__((address_space(1))) unsigned int*)(kb + sb + (size_t)(j0 + row) * TD_ + srcoff),
        (__attribute__((address_space(3))) unsigned int*)ldsB, 16, 0, 0);
    }
    __syncthreads();
    #pragma unroll
    for (int c0 = 0; c0 < 64; c0 += 32){
      bf16x8 af[4], bfr[4];
      #pragma unroll
      for (int mf = 0; mf < 4; ++mf){
        int row = wr * 64 + mf * 16 + lanelow;
        af[mf] = *(const bf16x8*)&As[row * 64 + ((c0 + kgrp * 8) ^ ((row & 7) * 8))];
      }
      #pragma unroll
      for (int nf = 0; nf < 4; ++nf){
        int row = wc * 64 + nf * 16 + lanelow;
        bfr[nf] = *(const bf16x8*)&Bs[row * 64 + ((c0 + kgrp * 8) ^ ((row & 7) * 8))];
      }
      #pragma unroll
      for (int mf = 0; mf < 4; ++mf)
        #pragma unroll
        for (int nf = 0; nf < 4; ++nf)
          acc[mf][nf] = __builtin_amdgcn_mfma_f32_16x16x32_bf16(af[mf], bfr[nf], acc[mf][nf], 0, 0, 0);
    }
  }

  float* outp = rlogp + ((size_t)p * H_ + h) * (L_ * L_);
  #pragma unroll
  for (int mf = 0; mf < 4; ++mf){
    int ibase = i0 + wr * 64 + mf * 16 + kgrp * 4;
    #pragma unroll
    for (int j2 = 0; j2 < 4; ++j2){
      float* orow = outp + (size_t)(ibase + j2) * L_ + j0 + wc * 64 + lanelow;
      #pragma unroll
      for (int nf = 0; nf < 4; ++nf)
        orow[nf * 16] = acc[mf][nf][j2];
    }
  }
}

// softmax over j: sums RSPLIT partials, scale+mask; writes fp32 maps (output) AND bf16 maps
__global__ __launch_bounds__(256) void row_softmax_kernel(
    const float* __restrict__ rlogp, const float* __restrict__ msum,
    float* __restrict__ maps, unsigned short* __restrict__ mapsb){
  int row = blockIdx.x;          // h*256 + i
  int t = threadIdx.x;
  float v = 0.f;
  #pragma unroll
  for (int pp = 0; pp < RSPLIT; ++pp)
    v += rlogp[(size_t)pp * (H_ * L_ * L_) + (size_t)row * L_ + t];
  v = v * (1.0f / 64.0f) + msum[t];
  __shared__ float red[8];
  float m = wred_max64(v);
  int wid = t >> 6;
  if ((t & 63) == 0) red[wid] = m;
  __syncthreads();
  float bm = fmaxf(fmaxf(red[0], red[1]), fmaxf(red[2], red[3]));
  float e = __expf(v - bm);
  float s = wred_sum64(e);
  if ((t & 63) == 0) red[4 + wid] = s;
  __syncthreads();
  float bs = (red[4] + red[5]) + (red[6] + red[7]);
  float p = e / bs;
  maps[(size_t)row * L_ + t] = p;
  mapsb[(size_t)row * L_ + t] = f2bf(p);
}

// VT[s,h,c,j] = V[s,j,h,c]  (bf16, LDS tile transpose, +1-padded rows)
__global__ __launch_bounds__(256) void vtrans_kernel(
    const unsigned short* __restrict__ qkvb, unsigned short* __restrict__ vt){
  __shared__ unsigned short T[64 * 265];
  int s = blockIdx.x, h = blockIdx.y;
  int t = threadIdx.x;
  const unsigned short* vb = qkvb + 2 * D_ + h * DH_;
  int jr = t >> 3, c0 = (t & 7) * 8;
  #pragma unroll
  for (int pass = 0; pass < 8; ++pass){
    int j = pass * 32 + jr;
    u16x8 r = *(const u16x8*)(vb + ((size_t)s * L_ + j) * TD_ + c0);
    #pragma unroll
    for (int e = 0; e < 8; ++e) T[(c0 + e) * 265 + j] = r[e];
  }
  __syncthreads();
  unsigned short* ob = vt + ((size_t)(s * H_ + h) * DH_) * L_;
  int c = t >> 2;
  #pragma unroll
  for (int u = 0; u < 8; ++u){
    int j0 = ((t & 3) + u * 4) * 8;
    u16x8 w;
    #pragma unroll
    for (int e = 0; e < 8; ++e) w[e] = T[c * 265 + j0 + e];
    *(u16x8*)(ob + (size_t)c * L_ + j0) = w;
  }
}

// rowtmp[s,i,h,c] = x[s,i,h,c] + sum_j mapsb[h,i,j] * VT[s,h,c,j]   (MFMA)
// 4 waves: wave w -> i in [w*64, w*64+64), all 64 c. K=256 over j, BK=32.
__global__ __launch_bounds__(256) void row_pv_mfma(
    const unsigned short* __restrict__ mapsb, const unsigned short* __restrict__ vt,
    const float* __restrict__ x, float* __restrict__ rowtmp){
  __shared__ unsigned short As[256*32] __attribute__((aligned(16)));
  __shared__ unsigned short Bs[64*32] __attribute__((aligned(16)));
  int s = blockIdx.x, h = blockIdx.y;
  int tid = threadIdx.x;
  int lane = tid & 63, wave = tid >> 6;
  int lanelow = lane & 15, kgrp = lane >> 4;

  f32x4 zero = {0.f, 0.f, 0.f, 0.f};
  f32x4 acc[4][4];
  #pragma unroll
  for (int mf = 0; mf < 4; ++mf)
    #pragma unroll
    for (int nf = 0; nf < 4; ++nf) acc[mf][nf] = zero;

  int srow = lane >> 2;
  int kchunk = (lane & 3) * 8;
  const unsigned short* Ag = mapsb + (size_t)h * (L_ * L_) + (size_t)(wave * 64 + srow) * L_ + kchunk;
  const unsigned short* Bg = vt + (((size_t)s * H_ + h) * DH_ + wave * 16 + srow) * L_ + kchunk;
  unsigned short* AsB = &As[(wave * 64) * 32];
  unsigned short* BsB = &Bs[(wave * 16) * 32];

  for (int k0 = 0; k0 < L_; k0 += 32){
    __syncthreads();
    #pragma unroll
    for (int u = 0; u < 4; ++u)
      __builtin_amdgcn_global_load_lds(
        (const __attribute__((address_space(1))) unsigned int*)(Ag + (size_t)u * 16 * L_ + k0),
        (__attribute__((address_space(3))) unsigned int*)(AsB + u * 16 * 32), 16, 0, 0);
    __builtin_amdgcn_global_load_lds(
      (const __attribute__((address_space(1))) unsigned int*)(Bg + k0),
      (__attribute__((address_space(3))) unsigned int*)(BsB), 16, 0, 0);
    __syncthreads();
    bf16x8 af[4], bfr[4];
    #pragma unroll
    for (int mf = 0; mf < 4; ++mf)
      af[mf] = *(const bf16x8*)&As[(wave * 64 + mf * 16 + lanelow) * 32 + kgrp * 8];
    #pragma unroll
    for (int nf = 0; nf < 4; ++nf)
      bfr[nf] = *(const bf16x8*)&Bs[(nf * 16 + lanelow) * 32 + kgrp * 8];
    #pragma unroll
    for (int mf = 0; mf < 4; ++mf)
      #pragma unroll
      for (int nf = 0; nf < 4; ++nf)
        acc[mf][nf] = __builtin_amdgcn_mfma_f32_16x16x32_bf16(af[mf], bfr[nf], acc[mf][nf], 0, 0, 0);
  }

  #pragma unroll
  for (int mf = 0; mf < 4; ++mf){
    int ibase = wave * 64 + mf * 16 + kgrp * 4;
    #pragma unroll
    for (int j2 = 0; j2 < 4; ++j2){
      size_t rb = ((size_t)s * L_ + ibase + j2) * D_ + h * DH_ + lanelow;
      #pragma unroll
      for (int nf = 0; nf < 4; ++nf)
        rowtmp[rb + nf * 16] = acc[mf][nf][j2] + x[rb + nf * 16];
    }
  }
}

// LN1: reads fp32 rowtmp, writes bf16 only (feeds gemm2 and the ln2 residual)
__global__ __launch_bounds__(256) void ln1_kernel(
    const float* __restrict__ a,
    const float* __restrict__ g, const float* __restrict__ be,
    unsigned short* __restrict__ outb){
  int row = blockIdx.x;
  int t = threadIdx.x;
  const float* pa = a + (size_t)row * D_;
  float v[3];
  float s1 = 0.f, s2 = 0.f;
  #pragma unroll
  for (int u = 0; u < 3; ++u){
    int c = t + u * 256;
    float xv = pa[c];
    v[u] = xv; s1 += xv; s2 += xv * xv;
  }
  s1 = wred_sum64(s1); s2 = wred_sum64(s2);
  __shared__ float red[8];
  int wid = t >> 6;
  if ((t & 63) == 0){ red[wid] = s1; red[4 + wid] = s2; }
  __syncthreads();
  float ts1 = (red[0] + red[1]) + (red[2] + red[3]);
  float ts2 = (red[4] + red[5]) + (red[6] + red[7]);
  float mu = ts1 * (1.0f / D_);
  float var = ts2 * (1.0f / D_) - mu * mu;
  float rs = rsqrtf(var + EPS_);
  #pragma unroll
  for (int u = 0; u < 3; ++u){
    int c = t + u * 256;
    outb[(size_t)row * D_ + c] = f2bf((v[u] - mu) * rs * g[c] + be[c]);
  }
}

// LN2: reads bf16 out1 + fp32 colout, writes fp32 final output
__global__ __launch_bounds__(256) void ln2_kernel(
    const unsigned short* __restrict__ ab,
    const float* __restrict__ b,
    const float* __restrict__ g, const float* __restrict__ be,
    float* __restrict__ out){
  int row = blockIdx.x;
  int t = threadIdx.x;
  const unsigned short* pa = ab + (size_t)row * D_;
  const float* pb = b + (size_t)row * D_;
  float v[3];
  float s1 = 0.f, s2 = 0.f;
  #pragma unroll
  for (int u = 0; u < 3; ++u){
    int c = t + u * 256;
    float xv = bf2f(pa[c]) + pb[c];
    v[u] = xv; s1 += xv; s2 += xv * xv;
  }
  s1 = wred_sum64(s1); s2 = wred_sum64(s2);
  __shared__ float red[8];
  int wid = t >> 6;
  if ((t & 63) == 0){ red[wid] = s1; red[4 + wid] = s2; }
  __syncthreads();
  float ts1 = (red[0] + red[1]) + (red[2] + red[3]);
  float ts2 = (red[4] + red[5]) + (red[6] + red[7]);
  float mu = ts1 * (1.0f / D_);
  float var = ts2 * (1.0f / D_) - mu * mu;
  float rs = rsqrtf(var + EPS_);
  #pragma unroll
  for (int u = 0; u < 3; ++u){
    int c = t + u * 256;
    out[(size_t)row * D_ + c] = (v[u] - mu) * rs * g[c] + be[c];
  }
}

// Column attention, one block per (l, h): 64x64 scores over E, softmax over j. (qkv in bf16)
__global__ __launch_bounds__(256) void col_attn_kernel(
    const unsigned short* __restrict__ qkvb, const int* __restrict__ pm,
    float* __restrict__ colout){
  int l = blockIdx.x;
  int h = blockIdx.y;
  __shared__ float Qs[64][64];
  __shared__ float Ks[64][64];
  __shared__ float Ps[64][65];
  int tid = threadIdx.x;
  int r = tid >> 2, cc = (tid & 3) << 4;
  const unsigned short* qb = qkvb + h * DH_;
  const unsigned short* kb = qkvb + D_ + h * DH_;
  const unsigned short* vb = qkvb + 2 * D_ + h * DH_;
  size_t rowbase = ((size_t)r * L_ + l) * TD_;
  #pragma unroll
  for (int u = 0; u < 2; ++u){
    u16x8 rq = *(const u16x8*)(qb + rowbase + cc + u * 8);
    u16x8 rk = *(const u16x8*)(kb + rowbase + cc + u * 8);
    #pragma unroll
    for (int e = 0; e < 8; ++e){
      Qs[r][cc + u * 8 + e] = bf2f(rq[e]);
      Ks[r][cc + u * 8 + e] = bf2f(rk[e]);
    }
  }
  __syncthreads();
  int i = tid >> 2, jq = tid & 3;
  float4 qreg[16];
  #pragma unroll
  for (int u = 0; u < 16; ++u) qreg[u] = *(const float4*)&Qs[i][u * 4];
  float vals[16];
  #pragma unroll
  for (int jj = 0; jj < 16; ++jj){
    int j = jq * 16 + jj;
    float dot = 0.f;
    #pragma unroll
    for (int u = 0; u < 16; ++u){
      float4 kv = *(const float4*)&Ks[j][u * 4];
      dot += qreg[u].x*kv.x + qreg[u].y*kv.y + qreg[u].z*kv.z + qreg[u].w*kv.w;
    }
    vals[jj] = dot * 0.125f + ((pm[j * L_ + l] != 0) ? NEGV : 0.f);
  }
  float m = -FLT_MAX;
  #pragma unroll
  for (int jj = 0; jj < 16; ++jj) m = fmaxf(m, vals[jj]);
  m = fmaxf(m, __shfl_xor(m, 1, 64));
  m = fmaxf(m, __shfl_xor(m, 2, 64));
  float sum = 0.f;
  #pragma unroll
  for (int jj = 0; jj < 16; ++jj){ vals[jj] = __expf(vals[jj] - m); sum += vals[jj]; }
  sum += __shfl_xor(sum, 1, 64);
  sum += __shfl_xor(sum, 2, 64);
  float inv = 1.0f / sum;
  #pragma unroll
  for (int jj = 0; jj < 16; ++jj) Ps[i][jq * 16 + jj] = vals[jj] * inv;
  __syncthreads();
  #pragma unroll
  for (int u = 0; u < 2; ++u){
    u16x8 rv = *(const u16x8*)(vb + rowbase + cc + u * 8);
    #pragma unroll
    for (int e = 0; e < 8; ++e) Qs[r][cc + u * 8 + e] = bf2f(rv[e]);
  }
  __syncthreads();
  int cq = tid & 3;
  float acc[16] = {};
  for (int j = 0; j < 64; ++j){
    float p = Ps[i][j];
    #pragma unroll
    for (int u = 0; u < 4; ++u){
      float4 vv = *(const float4*)&Qs[j][cq * 16 + u * 4];
      acc[u*4+0] = fmaf(p, vv.x, acc[u*4+0]);
      acc[u*4+1] = fmaf(p, vv.y, acc[u*4+1]);
      acc[u*4+2] = fmaf(p, vv.z, acc[u*4+2]);
      acc[u*4+3] = fmaf(p, vv.w, acc[u*4+3]);
    }
  }
  size_t ob = ((size_t)i * L_ + l) * D_ + h * DH_ + cq * 16;
  #pragma unroll
  for (int u = 0; u < 4; ++u){
    float4 o = {acc[u*4+0], acc[u*4+1], acc[u*4+2], acc[u*4+3]};
    *(float4*)(colout + ob + u * 4) = o;
  }
}

extern "C" void kernel_launch(void* const* d_in, const int* in_sizes, int n_in,
                              void* d_out, int out_size, void* d_ws, size_t ws_size,
                              hipStream_t stream){
  (void)in_sizes; (void)n_in; (void)out_size; (void)ws_size;
  const float* x     = (const float*)d_in[0];
  const int*   pm    = (const int*)  d_in[1];
  const float* w_row = (const float*)d_in[2];
  const float* b_row = (const float*)d_in[3];
  const float* w_col = (const float*)d_in[4];
  const float* b_col = (const float*)d_in[5];
  const float* g1    = (const float*)d_in[6];
  const float* be1   = (const float*)d_in[7];
  const float* g2    = (const float*)d_in[8];
  const float* be2   = (const float*)d_in[9];

  float* out  = (float*)d_out;                       // [64,256,768]
  float* maps = out + (size_t)E_ * L_ * D_;          // [12,256,256]

  // ws layout (float offsets) — total 52,494,592 f = 200.3 MiB (< proven 225.8)
  //   qkvb  @ 0            (18,874,368 f)
  //   tmpb  @ 18,874,368   (12,582,912 f)  rowtmp, later colout; xb aliases 1st half
  //   out1b @ 31,457,280   (6,291,456 f)
  //   msum  @ 37,748,736   (256 f)
  //   rlogp @ 37,748,992   (6,291,456 f)
  //   wrb   @ 44,040,448   (884,736 f)
  //   wcb   @ 44,925,184   (884,736 f)
  //   mapsb @ 45,809,920   (393,216 f = 786,432 bf16)
  //   vtb   @ 46,203,136   (6,291,456 f = 12.58M bf16)
  float* F    = (float*)d_ws;
  unsigned short* qkvb = (unsigned short*)F;
  float* tmpb = F + 18874368;
  unsigned short* out1b = (unsigned short*)(F + 31457280);
  float* msum = F + 37748736;
  float* rlogp = F + 37748992;
  unsigned short* wrb = (unsigned short*)(F + 44040448);
  unsigned short* wcb = (unsigned short*)(F + 44925184);
  unsigned short* mapsb = (unsigned short*)(F + 45809920);
  unsigned short* vtb = (unsigned short*)(F + 46203136);
  unsigned short* xb  = (unsigned short*)tmpb;   // dead before rowtmp is written

  const int M = E_ * L_;        // 16384
  const int NX = M * D_;        // 12,582,912
  const int NW = TD_ * D_;      // 1,769,472

  masksum_kernel<<<1, 256, 0, stream>>>(pm, msum);
  f2b_kernel<<<NX / 2048, 256, 0, stream>>>(x, xb);
  f2b_kernel<<<NW / 2048, 256, 0, stream>>>(w_row, wrb);
  f2b_kernel<<<NW / 2048, 256, 0, stream>>>(w_col, wcb);

  gemm_mfma_nt<<<dim3(GN/128, GM/128), 256, 0, stream>>>(xb, wrb, b_row, qkvb);
  vtrans_kernel<<<dim3(E_, H_), 256, 0, stream>>>(qkvb, vtb);
  row_logits_mfma<<<dim3(RSPLIT, 4, H_), 256, 0, stream>>>(qkvb, rlogp);
  row_softmax_kernel<<<H_ * L_, 256, 0, stream>>>(rlogp, msum, maps, mapsb);
  row_pv_mfma<<<dim3(E_, H_), 256, 0, stream>>>(mapsb, vtb, x, tmpb);
  ln1_kernel<<<M, 256, 0, stream>>>(tmpb, g1, be1, out1b);
  gemm_mfma_nt<<<dim3(GN/128, GM/128), 256, 0, stream>>>(out1b, wcb, b_col, qkvb);
  col_attn_kernel<<<dim3(L_, H_), 256, 0, stream>>>(qkvb, pm, tmpb);
  ln2_kernel<<<M, 256, 0, stream>>>(out1b, tmpb, g2, be2, out);
}

// Round 9
// 303.053 us; speedup vs baseline: 7.0479x; 1.3478x over previous
//
#include <hip/hip_runtime.h>
#include <hip/hip_bf16.h>
#include <float.h>

// Problem constants
#define E_  64
#define L_  256
#define D_  768
#define H_  12
#define DH_ 64
#define TD_ 2304     // 3*D
#define NEGV -10000.0f
#define EPS_ 1e-5f

#define GM 16384     // E_*L_
#define GN 2304      // TD_
#define GK 768       // D_

#define RSPLIT 8     // split-K factor for row_logits (over s)

typedef __attribute__((ext_vector_type(8))) __bf16 bf16x8;
typedef __attribute__((ext_vector_type(4))) float f32x4;
typedef __attribute__((ext_vector_type(8))) unsigned short u16x8;

__device__ __forceinline__ float wred_sum64(float v){
  #pragma unroll
  for (int o = 32; o > 0; o >>= 1) v += __shfl_xor(v, o, 64);
  return v;
}
__device__ __forceinline__ float wred_max64(float v){
  #pragma unroll
  for (int o = 32; o > 0; o >>= 1) v = fmaxf(v, __shfl_xor(v, o, 64));
  return v;
}
__device__ __forceinline__ unsigned short f2bf(float f){
  unsigned int u = __float_as_uint(f);
  u += 0x7FFF + ((u >> 16) & 1);   // round-to-nearest-even
  return (unsigned short)(u >> 16);
}
__device__ __forceinline__ float bf2f(unsigned short s){
  return __uint_as_float(((unsigned int)s) << 16);
}

// fp32 -> bf16, 8 elems/thread, exact grid (n % 2048 == 0)
__global__ __launch_bounds__(256) void f2b_kernel(
    const float* __restrict__ in, unsigned short* __restrict__ out){
  size_t i = ((size_t)blockIdx.x * 256 + threadIdx.x) * 8;
  float4 a = *(const float4*)(in + i);
  float4 b = *(const float4*)(in + i + 4);
  u16x8 o;
  o[0]=f2bf(a.x); o[1]=f2bf(a.y); o[2]=f2bf(a.z); o[3]=f2bf(a.w);
  o[4]=f2bf(b.x); o[5]=f2bf(b.y); o[6]=f2bf(b.z); o[7]=f2bf(b.w);
  *(u16x8*)(out + i) = o;
}

// msum[l] = -10000 * sum_s pm[s,l]
__global__ void masksum_kernel(const int* __restrict__ pm, float* __restrict__ msum){
  int l = threadIdx.x;
  int cnt = 0;
  #pragma unroll
  for (int s = 0; s < E_; ++s) cnt += (pm[s * L_ + l] != 0);
  msum[l] = NEGV * (float)cnt;
}

// C[GM,GN](bf16) = A[GM,GK](bf16) @ W[GN,GK](bf16)^T + bias.
__global__ __launch_bounds__(256) void gemm_mfma_nt(
    const unsigned short* __restrict__ A,
    const unsigned short* __restrict__ W,
    const float* __restrict__ bias,
    unsigned short* __restrict__ C){
  __shared__ unsigned short As[128*32] __attribute__((aligned(16)));
  __shared__ unsigned short Bs[128*32] __attribute__((aligned(16)));
  int tid = threadIdx.x;
  int lane = tid & 63, wave = tid >> 6;
  int wr = wave >> 1, wc = wave & 1;
  int m0 = blockIdx.y * 128, n0 = blockIdx.x * 128;
  int col16 = lane & 15, kgrp = lane >> 4;

  f32x4 zero = {0.f, 0.f, 0.f, 0.f};
  f32x4 acc[4][4];
  #pragma unroll
  for (int mf = 0; mf < 4; ++mf)
    #pragma unroll
    for (int nf = 0; nf < 4; ++nf) acc[mf][nf] = zero;

  int srow = lane >> 2;
  int kchunk = (lane & 3) * 8;
  const unsigned short* Ag = A + (size_t)(m0 + wave * 32 + srow) * GK + kchunk;
  const unsigned short* Wg = W + (size_t)(n0 + wave * 32 + srow) * GK + kchunk;
  unsigned short* AsB = &As[(wave * 32) * 32];   // wave-uniform LDS base
  unsigned short* BsB = &Bs[(wave * 32) * 32];

  for (int k0 = 0; k0 < GK; k0 += 32) {
    __syncthreads();
    __builtin_amdgcn_global_load_lds(
      (const __attribute__((address_space(1))) unsigned int*)(Ag + k0),
      (__attribute__((address_space(3))) unsigned int*)(AsB), 16, 0, 0);
    __builtin_amdgcn_global_load_lds(
      (const __attribute__((address_space(1))) unsigned int*)(Ag + 16 * GK + k0),
      (__attribute__((address_space(3))) unsigned int*)(AsB + 16 * 32), 16, 0, 0);
    __builtin_amdgcn_global_load_lds(
      (const __attribute__((address_space(1))) unsigned int*)(Wg + k0),
      (__attribute__((address_space(3))) unsigned int*)(BsB), 16, 0, 0);
    __builtin_amdgcn_global_load_lds(
      (const __attribute__((address_space(1))) unsigned int*)(Wg + 16 * GK + k0),
      (__attribute__((address_space(3))) unsigned int*)(BsB + 16 * 32), 16, 0, 0);
    __syncthreads();
    bf16x8 af[4], bfr[4];
    #pragma unroll
    for (int mf = 0; mf < 4; ++mf)
      af[mf] = *(const bf16x8*)&As[(wr * 64 + mf * 16 + col16) * 32 + kgrp * 8];
    #pragma unroll
    for (int nf = 0; nf < 4; ++nf)
      bfr[nf] = *(const bf16x8*)&Bs[(wc * 64 + nf * 16 + col16) * 32 + kgrp * 8];
    #pragma unroll
    for (int mf = 0; mf < 4; ++mf)
      #pragma unroll
      for (int nf = 0; nf < 4; ++nf)
        acc[mf][nf] = __builtin_amdgcn_mfma_f32_16x16x32_bf16(af[mf], bfr[nf], acc[mf][nf], 0, 0, 0);
  }

  float bv[4];
  #pragma unroll
  for (int nf = 0; nf < 4; ++nf) bv[nf] = bias[n0 + wc * 64 + nf * 16 + col16];
  #pragma unroll
  for (int mf = 0; mf < 4; ++mf){
    int rbase = m0 + wr * 64 + mf * 16 + kgrp * 4;
    #pragma unroll
    for (int j = 0; j < 4; ++j){
      unsigned short* crow = C + (size_t)(rbase + j) * GN + n0 + wc * 64 + col16;
      #pragma unroll
      for (int nf = 0; nf < 4; ++nf)
        crow[nf * 16] = f2bf(acc[mf][nf][j] + bv[nf]);
    }
  }
}

// rlogp[p,h,i,j] = sum_{s in split p, c} q[s,i,h,c]*k[s,j,h,c]   (bf16 MFMA)
__global__ __launch_bounds__(256) void row_logits_mfma(
    const unsigned short* __restrict__ qkvb, float* __restrict__ rlogp){
  __shared__ unsigned short As[128*64] __attribute__((aligned(16)));
  __shared__ unsigned short Bs[128*64] __attribute__((aligned(16)));
  int p = blockIdx.x;
  int tile = blockIdx.y;
  int h = blockIdx.z;
  int i0 = (tile >> 1) * 128, j0 = (tile & 1) * 128;
  int tid = threadIdx.x;
  int lane = tid & 63, wave = tid >> 6;
  int wr = wave >> 1, wc = wave & 1;
  int lanelow = lane & 15, kgrp = lane >> 4;

  f32x4 zero = {0.f, 0.f, 0.f, 0.f};
  f32x4 acc[4][4];
  #pragma unroll
  for (int mf = 0; mf < 4; ++mf)
    #pragma unroll
    for (int nf = 0; nf < 4; ++nf) acc[mf][nf] = zero;

  int cb8 = tid & 7;
  const unsigned short* qb = qkvb + h * DH_;
  const unsigned short* kb = qkvb + D_ + h * DH_;

  for (int ss = 0; ss < E_ / RSPLIT; ++ss){
    int s = p * (E_ / RSPLIT) + ss;
    size_t sb = (size_t)s * L_ * TD_;
    __syncthreads();
    #pragma unroll
    for (int q = 0; q < 4; ++q){
      int row = q * 32 + (tid >> 3);
      int srcoff = (cb8 * 8) ^ ((row & 7) * 8);
      unsigned short* ldsA = &As[(q * 256 + wave * 64) * 8];
      unsigned short* ldsB = &Bs[(q * 256 + wave * 64) * 8];
      __builtin_amdgcn_global_load_lds(
        (const __attribute__((address_space(1))) unsigned int*)(qb + sb + (size_t)(i0 + row) * TD_ + srcoff),
        (__attribute__((address_space(3))) unsigned int*)ldsA, 16, 0, 0);
      __builtin_amdgcn_global_load_lds(
        (const __attribute__((address_space(1))) unsigned int*)(kb + sb + (size_t)(j0 + row) * TD_ + srcoff),
        (__attribute__((address_space(3))) unsigned int*)ldsB, 16, 0, 0);
    }
    __syncthreads();
    #pragma unroll
    for (int c0 = 0; c0 < 64; c0 += 32){
      bf16x8 af[4], bfr[4];
      #pragma unroll
      for (int mf = 0; mf < 4; ++mf){
        int row = wr * 64 + mf * 16 + lanelow;
        af[mf] = *(const bf16x8*)&As[row * 64 + ((c0 + kgrp * 8) ^ ((row & 7) * 8))];
      }
      #pragma unroll
      for (int nf = 0; nf < 4; ++nf){
        int row = wc * 64 + nf * 16 + lanelow;
        bfr[nf] = *(const bf16x8*)&Bs[row * 64 + ((c0 + kgrp * 8) ^ ((row & 7) * 8))];
      }
      #pragma unroll
      for (int mf = 0; mf < 4; ++mf)
        #pragma unroll
        for (int nf = 0; nf < 4; ++nf)
          acc[mf][nf] = __builtin_amdgcn_mfma_f32_16x16x32_bf16(af[mf], bfr[nf], acc[mf][nf], 0, 0, 0);
    }
  }

  float* outp = rlogp + ((size_t)p * H_ + h) * (L_ * L_);
  #pragma unroll
  for (int mf = 0; mf < 4; ++mf){
    int ibase = i0 + wr * 64 + mf * 16 + kgrp * 4;
    #pragma unroll
    for (int j2 = 0; j2 < 4; ++j2){
      float* orow = outp + (size_t)(ibase + j2) * L_ + j0 + wc * 64 + lanelow;
      #pragma unroll
      for (int nf = 0; nf < 4; ++nf)
        orow[nf * 16] = acc[mf][nf][j2];
    }
  }
}

// softmax over j: sums RSPLIT partials, scale+mask; writes fp32 maps (output) AND bf16 maps
__global__ __launch_bounds__(256) void row_softmax_kernel(
    const float* __restrict__ rlogp, const float* __restrict__ msum,
    float* __restrict__ maps, unsigned short* __restrict__ mapsb){
  int row = blockIdx.x;          // h*256 + i
  int t = threadIdx.x;
  float v = 0.f;
  #pragma unroll
  for (int pp = 0; pp < RSPLIT; ++pp)
    v += rlogp[(size_t)pp * (H_ * L_ * L_) + (size_t)row * L_ + t];
  v = v * (1.0f / 64.0f) + msum[t];
  __shared__ float red[8];
  float m = wred_max64(v);
  int wid = t >> 6;
  if ((t & 63) == 0) red[wid] = m;
  __syncthreads();
  float bm = fmaxf(fmaxf(red[0], red[1]), fmaxf(red[2], red[3]));
  float e = __expf(v - bm);
  float s = wred_sum64(e);
  if ((t & 63) == 0) red[4 + wid] = s;
  __syncthreads();
  float bs = (red[4] + red[5]) + (red[6] + red[7]);
  float p = e / bs;
  maps[(size_t)row * L_ + t] = p;
  mapsb[(size_t)row * L_ + t] = f2bf(p);
}

// VT[s,h,c,j] = V[s,j,h,c]  (bf16, LDS tile transpose, +1-padded rows)
__global__ __launch_bounds__(256) void vtrans_kernel(
    const unsigned short* __restrict__ qkvb, unsigned short* __restrict__ vt){
  __shared__ unsigned short T[64 * 265];
  int s = blockIdx.x, h = blockIdx.y;
  int t = threadIdx.x;
  const unsigned short* vb = qkvb + 2 * D_ + h * DH_;
  int jr = t >> 3, c0 = (t & 7) * 8;
  #pragma unroll
  for (int pass = 0; pass < 8; ++pass){
    int j = pass * 32 + jr;
    u16x8 r = *(const u16x8*)(vb + ((size_t)s * L_ + j) * TD_ + c0);
    #pragma unroll
    for (int e = 0; e < 8; ++e) T[(c0 + e) * 265 + j] = r[e];
  }
  __syncthreads();
  unsigned short* ob = vt + ((size_t)(s * H_ + h) * DH_) * L_;
  int c = t >> 2;
  #pragma unroll
  for (int u = 0; u < 8; ++u){
    int j0 = ((t & 3) + u * 4) * 8;
    u16x8 w;
    #pragma unroll
    for (int e = 0; e < 8; ++e) w[e] = T[c * 265 + j0 + e];
    *(u16x8*)(ob + (size_t)c * L_ + j0) = w;
  }
}

// rowtmp[s,i,h,c] = x[s,i,h,c] + sum_j mapsb[h,i,j] * VT[s,h,c,j]   (MFMA)
__global__ __launch_bounds__(256) void row_pv_mfma(
    const unsigned short* __restrict__ mapsb, const unsigned short* __restrict__ vt,
    const float* __restrict__ x, float* __restrict__ rowtmp){
  __shared__ unsigned short As[256*32] __attribute__((aligned(16)));
  __shared__ unsigned short Bs[64*32] __attribute__((aligned(16)));
  int s = blockIdx.x, h = blockIdx.y;
  int tid = threadIdx.x;
  int lane = tid & 63, wave = tid >> 6;
  int lanelow = lane & 15, kgrp = lane >> 4;

  f32x4 zero = {0.f, 0.f, 0.f, 0.f};
  f32x4 acc[4][4];
  #pragma unroll
  for (int mf = 0; mf < 4; ++mf)
    #pragma unroll
    for (int nf = 0; nf < 4; ++nf) acc[mf][nf] = zero;

  int srow = lane >> 2;
  int kchunk = (lane & 3) * 8;
  const unsigned short* Ag = mapsb + (size_t)h * (L_ * L_) + (size_t)(wave * 64 + srow) * L_ + kchunk;
  const unsigned short* Bg = vt + (((size_t)s * H_ + h) * DH_ + wave * 16 + srow) * L_ + kchunk;
  unsigned short* AsB = &As[(wave * 64) * 32];
  unsigned short* BsB = &Bs[(wave * 16) * 32];

  for (int k0 = 0; k0 < L_; k0 += 32){
    __syncthreads();
    #pragma unroll
    for (int u = 0; u < 4; ++u)
      __builtin_amdgcn_global_load_lds(
        (const __attribute__((address_space(1))) unsigned int*)(Ag + (size_t)u * 16 * L_ + k0),
        (__attribute__((address_space(3))) unsigned int*)(AsB + u * 16 * 32), 16, 0, 0);
    __builtin_amdgcn_global_load_lds(
      (const __attribute__((address_space(1))) unsigned int*)(Bg + k0),
      (__attribute__((address_space(3))) unsigned int*)(BsB), 16, 0, 0);
    __syncthreads();
    bf16x8 af[4], bfr[4];
    #pragma unroll
    for (int mf = 0; mf < 4; ++mf)
      af[mf] = *(const bf16x8*)&As[(wave * 64 + mf * 16 + lanelow) * 32 + kgrp * 8];
    #pragma unroll
    for (int nf = 0; nf < 4; ++nf)
      bfr[nf] = *(const bf16x8*)&Bs[(nf * 16 + lanelow) * 32 + kgrp * 8];
    #pragma unroll
    for (int mf = 0; mf < 4; ++mf)
      #pragma unroll
      for (int nf = 0; nf < 4; ++nf)
        acc[mf][nf] = __builtin_amdgcn_mfma_f32_16x16x32_bf16(af[mf], bfr[nf], acc[mf][nf], 0, 0, 0);
  }

  #pragma unroll
  for (int mf = 0; mf < 4; ++mf){
    int ibase = wave * 64 + mf * 16 + kgrp * 4;
    #pragma unroll
    for (int j2 = 0; j2 < 4; ++j2){
      size_t rb = ((size_t)s * L_ + ibase + j2) * D_ + h * DH_ + lanelow;
      #pragma unroll
      for (int nf = 0; nf < 4; ++nf)
        rowtmp[rb + nf * 16] = acc[mf][nf][j2] + x[rb + nf * 16];
    }
  }
}

// LN1: reads fp32 rowtmp, writes bf16 only (feeds gemm2 and the ln2 residual)
__global__ __launch_bounds__(256) void ln1_kernel(
    const float* __restrict__ a,
    const float* __restrict__ g, const float* __restrict__ be,
    unsigned short* __restrict__ outb){
  int row = blockIdx.x;
  int t = threadIdx.x;
  const float* pa = a + (size_t)row * D_;
  float v[3];
  float s1 = 0.f, s2 = 0.f;
  #pragma unroll
  for (int u = 0; u < 3; ++u){
    int c = t + u * 256;
    float xv = pa[c];
    v[u] = xv; s1 += xv; s2 += xv * xv;
  }
  s1 = wred_sum64(s1); s2 = wred_sum64(s2);
  __shared__ float red[8];
  int wid = t >> 6;
  if ((t & 63) == 0){ red[wid] = s1; red[4 + wid] = s2; }
  __syncthreads();
  float ts1 = (red[0] + red[1]) + (red[2] + red[3]);
  float ts2 = (red[4] + red[5]) + (red[6] + red[7]);
  float mu = ts1 * (1.0f / D_);
  float var = ts2 * (1.0f / D_) - mu * mu;
  float rs = rsqrtf(var + EPS_);
  #pragma unroll
  for (int u = 0; u < 3; ++u){
    int c = t + u * 256;
    outb[(size_t)row * D_ + c] = f2bf((v[u] - mu) * rs * g[c] + be[c]);
  }
}

// LN2: reads bf16 out1 + fp32 colout, writes fp32 final output
__global__ __launch_bounds__(256) void ln2_kernel(
    const unsigned short* __restrict__ ab,
    const float* __restrict__ b,
    const float* __restrict__ g, const float* __restrict__ be,
    float* __restrict__ out){
  int row = blockIdx.x;
  int t = threadIdx.x;
  const unsigned short* pa = ab + (size_t)row * D_;
  const float* pb = b + (size_t)row * D_;
  float v[3];
  float s1 = 0.f, s2 = 0.f;
  #pragma unroll
  for (int u = 0; u < 3; ++u){
    int c = t + u * 256;
    float xv = bf2f(pa[c]) + pb[c];
    v[u] = xv; s1 += xv; s2 += xv * xv;
  }
  s1 = wred_sum64(s1); s2 = wred_sum64(s2);
  __shared__ float red[8];
  int wid = t >> 6;
  if ((t & 63) == 0){ red[wid] = s1; red[4 + wid] = s2; }
  __syncthreads();
  float ts1 = (red[0] + red[1]) + (red[2] + red[3]);
  float ts2 = (red[4] + red[5]) + (red[6] + red[7]);
  float mu = ts1 * (1.0f / D_);
  float var = ts2 * (1.0f / D_) - mu * mu;
  float rs = rsqrtf(var + EPS_);
  #pragma unroll
  for (int u = 0; u < 3; ++u){
    int c = t + u * 256;
    out[(size_t)row * D_ + c] = (v[u] - mu) * rs * g[c] + be[c];
  }
}

// Column attention via MFMA. One block per (l,h); 4 waves, wave w owns i-rows
// [w*16, w*16+16). Q,K row-major swizzled LDS; V transposed (Vt[c][j]) swizzled;
// P staged bf16 in swizzled LDS between QK-softmax and PV.
__global__ __launch_bounds__(256) void col_attn_mfma(
    const unsigned short* __restrict__ qkvb, const int* __restrict__ pm,
    float* __restrict__ colout){
  __shared__ unsigned short Qs[64*64] __attribute__((aligned(16)));
  __shared__ unsigned short Ks[64*64] __attribute__((aligned(16)));
  __shared__ unsigned short Vt[64*64] __attribute__((aligned(16)));
  __shared__ unsigned short Ps[64*64] __attribute__((aligned(16)));
  __shared__ float cmask[64];
  int l = blockIdx.x, h = blockIdx.y;
  int tid = threadIdx.x;
  int lane = tid & 63, wave = tid >> 6;
  int lanelow = lane & 15, kgrp = lane >> 4;

  const unsigned short* qb = qkvb + h * DH_;
  const unsigned short* kb = qkvb + D_ + h * DH_;
  const unsigned short* vb = qkvb + 2 * D_ + h * DH_;

  if (tid < 64) cmask[tid] = (pm[tid * L_ + l] != 0) ? NEGV : 0.f;

  // stage Q,K: [row][c] bf16, chunk-swizzle (chunk ^= row&7); vector 16B writes
  {
    int row = tid >> 3, ch = tid & 7;
    #pragma unroll
    for (int pass = 0; pass < 2; ++pass){
      int r2 = row + pass * 32;
      size_t gbase = ((size_t)r2 * L_ + l) * TD_ + ch * 8;
      u16x8 q8 = *(const u16x8*)(qb + gbase);
      u16x8 k8 = *(const u16x8*)(kb + gbase);
      int dst = r2 * 64 + ((ch ^ (r2 & 7)) * 8);
      *(u16x8*)&Qs[dst] = q8;
      *(u16x8*)&Ks[dst] = k8;
    }
  }
  // stage V transposed: Vt[c][j], chunk_j swizzled by c&7 (scalar scatter)
  {
    int jr = tid & 31, ch = tid >> 5;
    #pragma unroll
    for (int pass = 0; pass < 2; ++pass){
      int j = jr + pass * 32;
      u16x8 v8 = *(const u16x8*)(vb + ((size_t)j * L_ + l) * TD_ + ch * 8);
      #pragma unroll
      for (int e = 0; e < 8; ++e){
        int c = ch * 8 + e;
        Vt[c * 64 + (((j >> 3) ^ (c & 7)) * 8) + (j & 7)] = v8[e];
      }
    }
  }
  __syncthreads();

  // QK^T (scaled 1/8) : acc[nf][r] = S[i = wave*16+kgrp*4+r][j = nf*16+lanelow]
  f32x4 zero = {0.f, 0.f, 0.f, 0.f};
  f32x4 acc[4] = {zero, zero, zero, zero};
  int irow = wave * 16 + lanelow;
  #pragma unroll
  for (int ks = 0; ks < 2; ++ks){
    bf16x8 af = *(const bf16x8*)&Qs[irow * 64 + (((ks * 4 + kgrp) ^ (irow & 7)) * 8)];
    #pragma unroll
    for (int nf = 0; nf < 4; ++nf){
      int jrow = nf * 16 + lanelow;
      bf16x8 bk = *(const bf16x8*)&Ks[jrow * 64 + (((ks * 4 + kgrp) ^ (jrow & 7)) * 8)];
      acc[nf] = __builtin_amdgcn_mfma_f32_16x16x32_bf16(af, bk, acc[nf], 0, 0, 0);
    }
  }
  float cm[4];
  #pragma unroll
  for (int nf = 0; nf < 4; ++nf) cm[nf] = cmask[nf * 16 + lanelow];
  #pragma unroll
  for (int r = 0; r < 4; ++r){
    float pvv[4];
    float m = -FLT_MAX;
    #pragma unroll
    for (int nf = 0; nf < 4; ++nf){
      pvv[nf] = acc[nf][r] * 0.125f + cm[nf];
      m = fmaxf(m, pvv[nf]);
    }
    m = fmaxf(m, __shfl_xor(m, 1, 64));
    m = fmaxf(m, __shfl_xor(m, 2, 64));
    m = fmaxf(m, __shfl_xor(m, 4, 64));
    m = fmaxf(m, __shfl_xor(m, 8, 64));
    float s = 0.f;
    #pragma unroll
    for (int nf = 0; nf < 4; ++nf){ pvv[nf] = __expf(pvv[nf] - m); s += pvv[nf]; }
    s += __shfl_xor(s, 1, 64);
    s += __shfl_xor(s, 2, 64);
    s += __shfl_xor(s, 4, 64);
    s += __shfl_xor(s, 8, 64);
    float inv = 1.0f / s;
    int i = wave * 16 + kgrp * 4 + r;
    #pragma unroll
    for (int nf = 0; nf < 4; ++nf){
      int j = nf * 16 + lanelow;
      Ps[i * 64 + (((j >> 3) ^ (i & 7)) * 8) + (j & 7)] = f2bf(pvv[nf] * inv);
    }
  }
  __syncthreads();

  // PV: O[i,c] = sum_j P[i,j] * Vt[c][j]
  f32x4 acc2[4] = {zero, zero, zero, zero};
  #pragma unroll
  for (int ks = 0; ks < 2; ++ks){
    bf16x8 pa = *(const bf16x8*)&Ps[irow * 64 + (((ks * 4 + kgrp) ^ (irow & 7)) * 8)];
    #pragma unroll
    for (int nf = 0; nf < 4; ++nf){
      int crow = nf * 16 + lanelow;
      bf16x8 bv = *(const bf16x8*)&Vt[crow * 64 + (((ks * 4 + kgrp) ^ (crow & 7)) * 8)];
      acc2[nf] = __builtin_amdgcn_mfma_f32_16x16x32_bf16(pa, bv, acc2[nf], 0, 0, 0);
    }
  }
  #pragma unroll
  for (int r = 0; r < 4; ++r){
    int i = wave * 16 + kgrp * 4 + r;
    size_t ob = ((size_t)i * L_ + l) * D_ + h * DH_ + lanelow;
    #pragma unroll
    for (int nf = 0; nf < 4; ++nf)
      colout[ob + nf * 16] = acc2[nf][r];
  }
}

extern "C" void kernel_launch(void* const* d_in, const int* in_sizes, int n_in,
                              void* d_out, int out_size, void* d_ws, size_t ws_size,
                              hipStream_t stream){
  (void)in_sizes; (void)n_in; (void)out_size; (void)ws_size;
  const float* x     = (const float*)d_in[0];
  const int*   pm    = (const int*)  d_in[1];
  const float* w_row = (const float*)d_in[2];
  const float* b_row = (const float*)d_in[3];
  const float* w_col = (const float*)d_in[4];
  const float* b_col = (const float*)d_in[5];
  const float* g1    = (const float*)d_in[6];
  const float* be1   = (const float*)d_in[7];
  const float* g2    = (const float*)d_in[8];
  const float* be2   = (const float*)d_in[9];

  float* out  = (float*)d_out;                       // [64,256,768]
  float* maps = out + (size_t)E_ * L_ * D_;          // [12,256,256]

  // ws layout (float offsets) — total 52,494,592 f = 200.3 MiB (< proven 225.8)
  float* F    = (float*)d_ws;
  unsigned short* qkvb = (unsigned short*)F;
  float* tmpb = F + 18874368;
  unsigned short* out1b = (unsigned short*)(F + 31457280);
  float* msum = F + 37748736;
  float* rlogp = F + 37748992;
  unsigned short* wrb = (unsigned short*)(F + 44040448);
  unsigned short* wcb = (unsigned short*)(F + 44925184);
  unsigned short* mapsb = (unsigned short*)(F + 45809920);
  unsigned short* vtb = (unsigned short*)(F + 46203136);
  unsigned short* xb  = (unsigned short*)tmpb;   // dead before rowtmp is written

  const int M = E_ * L_;        // 16384
  const int NX = M * D_;        // 12,582,912
  const int NW = TD_ * D_;      // 1,769,472

  masksum_kernel<<<1, 256, 0, stream>>>(pm, msum);
  f2b_kernel<<<NX / 2048, 256, 0, stream>>>(x, xb);
  f2b_kernel<<<NW / 2048, 256, 0, stream>>>(w_row, wrb);
  f2b_kernel<<<NW / 2048, 256, 0, stream>>>(w_col, wcb);

  gemm_mfma_nt<<<dim3(GN/128, GM/128), 256, 0, stream>>>(xb, wrb, b_row, qkvb);
  vtrans_kernel<<<dim3(E_, H_), 256, 0, stream>>>(qkvb, vtb);
  row_logits_mfma<<<dim3(RSPLIT, 4, H_), 256, 0, stream>>>(qkvb, rlogp);
  row_softmax_kernel<<<H_ * L_, 256, 0, stream>>>(rlogp, msum, maps, mapsb);
  row_pv_mfma<<<dim3(E_, H_), 256, 0, stream>>>(mapsb, vtb, x, tmpb);
  ln1_kernel<<<M, 256, 0, stream>>>(tmpb, g1, be1, out1b);
  gemm_mfma_nt<<<dim3(GN/128, GM/128), 256, 0, stream>>>(out1b, wcb, b_col, qkvb);
  col_attn_mfma<<<dim3(L_, H_), 256, 0, stream>>>(qkvb, pm, tmpb);
  ln2_kernel<<<M, 256, 0, stream>>>(out1b, tmpb, g2, be2, out);
}